// Round 1
// 4440.095 us; speedup vs baseline: 1.4643x; 1.4643x over previous
//
#include <hip/hip_runtime.h>
#include <hip/hip_bf16.h>
#include <math.h>

#define N_LAYERS 4
#define NHEADS 16
#define LOOKBACK 128

typedef unsigned short ushort_t;
typedef __attribute__((ext_vector_type(8))) short short8;
typedef __attribute__((ext_vector_type(4))) float f32x4;

__device__ __forceinline__ ushort_t f2bf(float f) {
    union { float f; unsigned int u; } v; v.f = f;
    unsigned int r = (v.u + 0x7FFFu + ((v.u >> 16) & 1u)) >> 16;
    return (ushort_t)r;
}
__device__ __forceinline__ float bf2f(ushort_t s) {
    union { unsigned int u; float f; } v; v.u = ((unsigned int)s) << 16;
    return v.f;
}

// ---------------- block reductions (blockDim == 256, 4 waves) ----------------
__device__ __forceinline__ float blk_max(float v, volatile float* red) {
#pragma unroll
    for (int o = 32; o > 0; o >>= 1) v = fmaxf(v, __shfl_down(v, o, 64));
    if ((threadIdx.x & 63) == 0) red[threadIdx.x >> 6] = v;
    __syncthreads();
    float r = fmaxf(fmaxf(red[0], red[1]), fmaxf(red[2], red[3]));
    __syncthreads();
    return r;
}
__device__ __forceinline__ float blk_sum(float v, volatile float* red) {
#pragma unroll
    for (int o = 32; o > 0; o >>= 1) v += __shfl_down(v, o, 64);
    if ((threadIdx.x & 63) == 0) red[threadIdx.x >> 6] = v;
    __syncthreads();
    float r = red[0] + red[1] + red[2] + red[3];
    __syncthreads();
    return r;
}

// ---------------- fp32 -> bf16 convert ----------------
__global__ __launch_bounds__(256) void f2b_k(const float* __restrict__ in,
                                             ushort_t* __restrict__ out, int n4) {
    int i = blockIdx.x * 256 + threadIdx.x;
    if (i >= n4) return;
    float4 v = *(const float4*)(in + (size_t)i * 4);
    ushort_t* o = out + (size_t)i * 4;
    o[0] = f2bf(v.x); o[1] = f2bf(v.y); o[2] = f2bf(v.z); o[3] = f2bf(v.w);
}

// ---------------- RMSNorm -> bf16 out ----------------
__global__ __launch_bounds__(256) void rmsnorm_bf(const float* __restrict__ x,
                                                  const float* __restrict__ w,
                                                  ushort_t* __restrict__ out, int D) {
    __shared__ float red[4];
    size_t row = blockIdx.x;
    const float* xr = x + row * D;
    float ss = 0.f;
    for (int i = threadIdx.x; i < D; i += 256) { float v = xr[i]; ss += v * v; }
    float tot = blk_sum(ss, red);
    float r = rsqrtf(tot / (float)D + 1e-6f);
    ushort_t* o = out + row * D;
    for (int i = threadIdx.x; i < D; i += 256) o[i] = f2bf(xr[i] * r * w[i]);
}

// ---------------- RMSNorm -> fp32 out (final) ----------------
__global__ __launch_bounds__(256) void rmsnorm_k(const float* __restrict__ x,
                                                 const float* __restrict__ w,
                                                 float* __restrict__ out, int D) {
    __shared__ float red[4];
    size_t row = blockIdx.x;
    const float* xr = x + row * D;
    float ss = 0.f;
    for (int i = threadIdx.x; i < D; i += 256) { float v = xr[i]; ss += v * v; }
    float tot = blk_sum(ss, red);
    float r = rsqrtf(tot / (float)D + 1e-6f);
    float* o = out + row * D;
    for (int i = threadIdx.x; i < D; i += 256) o[i] = xr[i] * r * w[i];
}

// ---------------- bf16 MFMA NT-GEMM (m97 structure) ----------------
// C[m,n] = sum_k A[m,k] * W[n,k]; A,W bf16 row-major; acc fp32.
// 128x128 tile, BK=32, 4 waves, each wave 64x64 via 4x4 mfma_16x16x32.
#define GBM 128
#define GBN 128
#define GBK 32

__global__ __launch_bounds__(256) void gemm_bf16(
    const ushort_t* __restrict__ A, const ushort_t* __restrict__ Bw,
    void* __restrict__ Cout, const float* __restrict__ bias,
    const float* __restrict__ resid, const ushort_t* __restrict__ gate,
    int M, int N, int K, int out_bf16) {
    __shared__ ushort_t As[GBM * GBK];
    __shared__ ushort_t Bs[GBN * GBK];
    int tid = threadIdx.x;
    int wave = tid >> 6, lane = tid & 63;
    int bm = blockIdx.y * GBM, bn = blockIdx.x * GBN;
    int wm = (wave & 1) * 64, wn = (wave >> 1) * 64;
    int r4 = lane >> 2, c4 = lane & 3;        // staging: row-in-16, 16B chunk
    int r = lane & 15, q = lane >> 4;         // mfma lane decomposition

    f32x4 acc[4][4];
#pragma unroll
    for (int i = 0; i < 4; ++i)
#pragma unroll
        for (int j = 0; j < 4; ++j) acc[i][j] = (f32x4){0.f, 0.f, 0.f, 0.f};

    int srow = wave * 16 + r4;
    for (int k0 = 0; k0 < K; k0 += GBK) {
        const ushort_t* Ag = A + (size_t)(bm + srow) * K + k0 + c4 * 8;
        const ushort_t* Bg = Bw + (size_t)(bn + srow) * K + k0 + c4 * 8;
        __builtin_amdgcn_global_load_lds(
            (const __attribute__((address_space(1))) void*)Ag,
            (__attribute__((address_space(3))) void*)&As[wave * 16 * GBK],
            16, 0, 0);
        __builtin_amdgcn_global_load_lds(
            (const __attribute__((address_space(1))) void*)(Ag + (size_t)64 * K),
            (__attribute__((address_space(3))) void*)&As[(64 + wave * 16) * GBK],
            16, 0, 0);
        __builtin_amdgcn_global_load_lds(
            (const __attribute__((address_space(1))) void*)Bg,
            (__attribute__((address_space(3))) void*)&Bs[wave * 16 * GBK],
            16, 0, 0);
        __builtin_amdgcn_global_load_lds(
            (const __attribute__((address_space(1))) void*)(Bg + (size_t)64 * K),
            (__attribute__((address_space(3))) void*)&Bs[(64 + wave * 16) * GBK],
            16, 0, 0);
        __syncthreads();
        short8 af[4], bfr[4];
#pragma unroll
        for (int i = 0; i < 4; ++i)
            af[i] = *(const short8*)&As[(wm + 16 * i + r) * GBK + q * 8];
#pragma unroll
        for (int j = 0; j < 4; ++j)
            bfr[j] = *(const short8*)&Bs[(wn + 16 * j + r) * GBK + q * 8];
#pragma unroll
        for (int i = 0; i < 4; ++i)
#pragma unroll
            for (int j = 0; j < 4; ++j)
                acc[i][j] = __builtin_amdgcn_mfma_f32_16x16x32_bf16(
                    af[i], bfr[j], acc[i][j], 0, 0, 0);
        __syncthreads();
    }
    // epilogue: row = bm+wm+16i+q*4+t, col = bn+wn+16j+r
#pragma unroll
    for (int i = 0; i < 4; ++i) {
#pragma unroll
        for (int j = 0; j < 4; ++j) {
            size_t n = (size_t)(bn + wn + 16 * j + r);
            float bn_v = bias ? bias[n] : 0.f;
#pragma unroll
            for (int t = 0; t < 4; ++t) {
                size_t m = (size_t)(bm + wm + 16 * i + q * 4 + t);
                size_t idx = m * N + n;
                float x = acc[i][j][t] + bn_v;
                if (gate) { float g = bf2f(gate[idx]); x *= g / (1.0f + __expf(-g)); }
                if (resid) x += resid[idx];
                if (out_bf16) ((ushort_t*)Cout)[idx] = f2bf(x);
                else ((float*)Cout)[idx] = x;
            }
        }
    }
}

// ---------------- RoPE in place on bf16 qkv; Q also scaled by 1/sqrt(d) -----
__global__ void rope_k(ushort_t* __restrict__ qkv, int L, int total) {
    int idx = blockIdx.x * 256 + threadIdx.x;
    if (idx >= total) return;
    int d = idx & 31;
    int h = (idx >> 5) & 15;
    int bl = idx >> 9;
    int l = bl % L;
    float inv = powf(10000.0f, -(float)d * (1.0f / 32.0f));
    float f = (float)l * inv;
    float s, c;
    sincosf(f, &s, &c);
    ushort_t* base = qkv + (size_t)bl * 3072 + h * 64 + d;
    float x1 = bf2f(base[0]), x2 = bf2f(base[32]);
    base[0]  = f2bf((x1 * c - x2 * s) * 0.125f);   // Q pre-scaled
    base[32] = f2bf((x2 * c + x1 * s) * 0.125f);
    ushort_t* kb = base + 1024;
    x1 = bf2f(kb[0]); x2 = bf2f(kb[32]);
    kb[0]  = f2bf(x1 * c - x2 * s);
    kb[32] = f2bf(x2 * c + x1 * s);
}

// ---------------- flash self-attention: MFMA, 64q x 64k tiles ---------------
// qkv is bf16, Q already scaled. 4 waves, each owns a 16-row q strip.
// Fragment/C layouts identical to gemm_bf16 (m97-verified):
//   a/b-frag: row = lane&15, k-chunk = (lane>>4)*8
//   C:        row = (lane>>4)*4 + t, col = lane&15
#define AP 72   // padded LDS row (bf16 elems); 144B stride, 16B-aligned

__global__ __launch_bounds__(256) void self_attn_flash(
    const ushort_t* __restrict__ qkv, ushort_t* __restrict__ out, int L) {
    int qt = blockIdx.x, h = blockIdx.y, b = blockIdx.z;
    int q0 = qt * 64;
    __shared__ ushort_t Qs[64 * AP];
    __shared__ ushort_t Ks[64 * AP];
    __shared__ ushort_t VT[64 * AP];   // VT[d][k] = V[k][d]
    __shared__ ushort_t Ps[64 * AP];   // 4 waves x 16 rows of P (bf16)
    int tid = threadIdx.x;
    int wave = tid >> 6, lane = tid & 63;
    int g = lane >> 4, r = lane & 15;
    int lr = tid >> 2, lc = tid & 3;   // staging: row, 16-elem chunk

    // stage Q once (bf16 copy, already scaled)
    {
        const ushort_t* src = qkv + ((size_t)b * L + q0 + lr) * 3072 + h * 64 + lc * 16;
        *(short8*)&Qs[lr * AP + lc * 16]     = *(const short8*)(src);
        *(short8*)&Qs[lr * AP + lc * 16 + 8] = *(const short8*)(src + 8);
    }

    float m[4]    = {-1e30f, -1e30f, -1e30f, -1e30f};
    float lsum[4] = {0.f, 0.f, 0.f, 0.f};
    f32x4 acc[4];
#pragma unroll
    for (int j = 0; j < 4; ++j) acc[j] = (f32x4){0.f, 0.f, 0.f, 0.f};

    for (int kt = 0; kt <= qt; ++kt) {
        int k0 = kt * 64;
        __syncthreads();
        {
            const ushort_t* ksrc = qkv + ((size_t)b * L + k0 + lr) * 3072 + 1024 + h * 64 + lc * 16;
            short8 k0v = *(const short8*)(ksrc);
            short8 k1v = *(const short8*)(ksrc + 8);
            *(short8*)&Ks[lr * AP + lc * 16]     = k0v;
            *(short8*)&Ks[lr * AP + lc * 16 + 8] = k1v;
            const ushort_t* vsrc = ksrc + 1024;
            short8 v0v = *(const short8*)(vsrc);
            short8 v1v = *(const short8*)(vsrc + 8);
#pragma unroll
            for (int i = 0; i < 8; ++i) {
                VT[(lc * 16 + i) * AP + lr]     = (ushort_t)v0v[i];
                VT[(lc * 16 + 8 + i) * AP + lr] = (ushort_t)v1v[i];
            }
        }
        __syncthreads();

        // S = Q_strip(16x64) . K^T(64x64)
        f32x4 s[4];
#pragma unroll
        for (int j = 0; j < 4; ++j) s[j] = (f32x4){0.f, 0.f, 0.f, 0.f};
        short8 aq[2];
#pragma unroll
        for (int c = 0; c < 2; ++c)
            aq[c] = *(const short8*)&Qs[(wave * 16 + r) * AP + c * 32 + g * 8];
#pragma unroll
        for (int j = 0; j < 4; ++j)
#pragma unroll
            for (int c = 0; c < 2; ++c) {
                short8 bk = *(const short8*)&Ks[(16 * j + r) * AP + c * 32 + g * 8];
                s[j] = __builtin_amdgcn_mfma_f32_16x16x32_bf16(aq[c], bk, s[j], 0, 0, 0);
            }

        // causal mask on diagonal tile: k(16j+r) > q(16*wave+4g+t)
        if (kt == qt) {
#pragma unroll
            for (int j = 0; j < 4; ++j)
#pragma unroll
                for (int t = 0; t < 4; ++t)
                    if (16 * j + r > 16 * wave + 4 * g + t) s[j][t] = -1e30f;
        }

        // online softmax; each lane handles rows 4g+t, replicated over r
        float al[4];
#pragma unroll
        for (int t = 0; t < 4; ++t) {
            float rm = fmaxf(fmaxf(s[0][t], s[1][t]), fmaxf(s[2][t], s[3][t]));
#pragma unroll
            for (int o = 8; o > 0; o >>= 1) rm = fmaxf(rm, __shfl_xor(rm, o, 16));
            float mn = fmaxf(m[t], rm);
            al[t] = __expf(m[t] - mn);
            m[t] = mn;
            float rs = 0.f;
#pragma unroll
            for (int j = 0; j < 4; ++j) {
                float p = __expf(s[j][t] - mn);
                s[j][t] = p;
                rs += p;
            }
#pragma unroll
            for (int o = 8; o > 0; o >>= 1) rs += __shfl_xor(rs, o, 16);
            lsum[t] = lsum[t] * al[t] + rs;
        }

        // P -> LDS (bf16, C-layout) then re-read as a-frags. Same-wave only.
        ushort_t* pw = &Ps[wave * 16 * AP];
#pragma unroll
        for (int j = 0; j < 4; ++j)
#pragma unroll
            for (int t = 0; t < 4; ++t)
                pw[(4 * g + t) * AP + 16 * j + r] = f2bf(s[j][t]);
        short8 ap[2];
#pragma unroll
        for (int c = 0; c < 2; ++c)
            ap[c] = *(const short8*)&pw[r * AP + c * 32 + g * 8];

        // rescale O then accumulate P.V via V^T b-frags
#pragma unroll
        for (int j = 0; j < 4; ++j) {
#pragma unroll
            for (int t = 0; t < 4; ++t) acc[j][t] *= al[t];
#pragma unroll
            for (int c = 0; c < 2; ++c) {
                short8 bv = *(const short8*)&VT[(16 * j + r) * AP + c * 32 + g * 8];
                acc[j] = __builtin_amdgcn_mfma_f32_16x16x32_bf16(ap[c], bv, acc[j], 0, 0, 0);
            }
        }
    }

    // epilogue: row = q0+16*wave+4g+t, col = h*64+16j+r
#pragma unroll
    for (int t = 0; t < 4; ++t) {
        float invl = 1.0f / lsum[t];
        size_t orow = ((size_t)b * L + q0 + wave * 16 + 4 * g + t) * 1024 + h * 64;
#pragma unroll
        for (int j = 0; j < 4; ++j)
            out[orow + 16 * j + r] = f2bf(acc[j][t] * invl);
    }
}

// ---------------- cross-attention, bf16 out ----------------
__global__ __launch_bounds__(256) void cross_attn_k(
    const float* __restrict__ qc, const float* __restrict__ kv,
    const int* __restrict__ seg_ids, ushort_t* __restrict__ out, int L, int S) {
    int l = blockIdx.x, h = blockIdx.y, b = blockIdx.z;
    __shared__ float qs[64];
    __shared__ float sc[LOOKBACK];
    __shared__ float red[4];
    __shared__ float pv[4][64];
    int tid = threadIdx.x;
    int seg = seg_ids[(size_t)b * L + l];
    int k0 = seg - LOOKBACK + 1; if (k0 < 0) k0 = 0;
    int nk = seg - k0 + 1;
    if (tid < 64) qs[tid] = qc[((size_t)b * L + l) * 1024 + h * 64 + tid];
    __syncthreads();
    float lmax = -1e30f;
    if (tid < nk) {
        int k = k0 + tid;
        const float* kr = kv + ((size_t)b * S + k) * 2048 + h * 64;
        float s = 0.f;
#pragma unroll
        for (int d = 0; d < 64; d += 4) {
            float4 k4 = *(const float4*)(kr + d);
            s += qs[d] * k4.x + qs[d + 1] * k4.y + qs[d + 2] * k4.z + qs[d + 3] * k4.w;
        }
        s *= 0.125f;
        sc[tid] = s;
        lmax = s;
    }
    float gmax = blk_max(lmax, red);
    float lsum = 0.f;
    if (tid < nk) {
        float p = __expf(sc[tid] - gmax);
        sc[tid] = p;
        lsum = p;
    }
    float gsum = blk_sum(lsum, red);
    float inv = 1.0f / gsum;
    int d = tid & 63, part = tid >> 6;
    float acc = 0.f;
    for (int kk = part; kk < nk; kk += 4)
        acc += sc[kk] * kv[((size_t)b * S + k0 + kk) * 2048 + 1024 + h * 64 + d];
    pv[part][d] = acc;
    __syncthreads();
    if (tid < 64) {
        float r = (pv[0][tid] + pv[1][tid] + pv[2][tid] + pv[3][tid]) * inv;
        out[((size_t)b * L + l) * 1024 + h * 64 + tid] = f2bf(r);
    }
}

// ---------------- driver ----------------
extern "C" void kernel_launch(void* const* d_in, const int* in_sizes, int n_in,
                              void* d_out, int out_size, void* d_ws, size_t ws_size,
                              hipStream_t stream) {
    const int B = 2, L = 2048, S = 256, D = 1024, F = 4096;
    const int BL = B * L;
    const float* x_in   = (const float*)d_in[0];
    const float* memory = (const float*)d_in[1];
    const int*   seg    = (const int*)d_in[2];
    const float* Wqkv = (const float*)d_in[3];
    const float* bqkv = (const float*)d_in[4];
    const float* Wo   = (const float*)d_in[5];
    const float* bo   = (const float*)d_in[6];
    const float* Wq_c = (const float*)d_in[7];
    const float* Wkv_c= (const float*)d_in[8];
    const float* Wo_c = (const float*)d_in[9];
    const float* Wg   = (const float*)d_in[10];
    const float* Wu   = (const float*)d_in[11];
    const float* Wd   = (const float*)d_in[12];
    const float* n1   = (const float*)d_in[13];
    const float* n2   = (const float*)d_in[14];
    const float* n3   = (const float*)d_in[15];
    const float* nf   = (const float*)d_in[16];

    char* ws = (char*)d_ws;
    size_t off = 0;
    float* X     = (float*)(ws + off); off += (size_t)BL * D * 4;        // 16 MB
    float* QKV   = (float*)(ws + off); off += (size_t)BL * 3 * D * 4;    // 48 MB (aliases QKVb, Qc, Gg)
    float* KVC   = (float*)(ws + off); off += (size_t)B * S * 2 * D * 4; // 4 MB
    ushort_t* Hn  = (ushort_t*)(ws + off); off += (size_t)BL * D * 2;    // 8 MB
    ushort_t* Abf = (ushort_t*)(ws + off); off += (size_t)BL * D * 2;    // 8 MB
    ushort_t* Mb  = (ushort_t*)(ws + off); off += (size_t)B * S * D * 2; // 1 MB
    ushort_t* Wb  = (ushort_t*)(ws + off); off += (size_t)F * D * 2;     // 8 MB
    ushort_t* QKVb = (ushort_t*)QKV;    // bf16 view, self-attn phase
    float* Qc = QKV;                    // fp32 view, cross phase
    ushort_t* Gg = (ushort_t*)QKV;      // bf16 view, MLP phase

    hipMemcpyAsync(X, x_in, (size_t)BL * D * sizeof(float), hipMemcpyDeviceToDevice, stream);

    dim3 blk(256);
    // memory -> bf16 once
    f2b_k<<<(B * S * D / 4 + 255) / 256, blk, 0, stream>>>(memory, Mb, B * S * D / 4);

    for (int l = 0; l < N_LAYERS; ++l) {
        // ---- self-attention block ----
        rmsnorm_bf<<<BL, blk, 0, stream>>>(X, n1 + (size_t)l * D, Hn, D);
        f2b_k<<<(3 * D * D / 4 + 255) / 256, blk, 0, stream>>>(
            Wqkv + (size_t)l * 3 * D * D, Wb, 3 * D * D / 4);
        gemm_bf16<<<dim3(3 * D / GBN, BL / GBM), blk, 0, stream>>>(
            Hn, Wb, QKVb, bqkv + (size_t)l * 3 * D, nullptr, nullptr, BL, 3 * D, D, 1);
        int total = BL * NHEADS * 32;
        rope_k<<<(total + 255) / 256, blk, 0, stream>>>(QKVb, L, total);
        self_attn_flash<<<dim3(L / 64, NHEADS, B), blk, 0, stream>>>(QKVb, Abf, L);
        f2b_k<<<(D * D / 4 + 255) / 256, blk, 0, stream>>>(
            Wo + (size_t)l * D * D, Wb, D * D / 4);
        gemm_bf16<<<dim3(D / GBN, BL / GBM), blk, 0, stream>>>(
            Abf, Wb, X, bo + (size_t)l * D, X, nullptr, BL, D, D, 0);
        // ---- cross-attention block ----
        rmsnorm_bf<<<BL, blk, 0, stream>>>(X, n2 + (size_t)l * D, Hn, D);
        f2b_k<<<(D * D / 4 + 255) / 256, blk, 0, stream>>>(
            Wq_c + (size_t)l * D * D, Wb, D * D / 4);
        gemm_bf16<<<dim3(D / GBN, BL / GBM), blk, 0, stream>>>(
            Hn, Wb, Qc, nullptr, nullptr, nullptr, BL, D, D, 0);
        f2b_k<<<(2 * D * D / 4 + 255) / 256, blk, 0, stream>>>(
            Wkv_c + (size_t)l * 2 * D * D, Wb, 2 * D * D / 4);
        gemm_bf16<<<dim3(2 * D / GBN, B * S / GBM), blk, 0, stream>>>(
            Mb, Wb, KVC, nullptr, nullptr, nullptr, B * S, 2 * D, D, 0);
        cross_attn_k<<<dim3(L, NHEADS, B), blk, 0, stream>>>(Qc, KVC, seg, Abf, L, S);
        f2b_k<<<(D * D / 4 + 255) / 256, blk, 0, stream>>>(
            Wo_c + (size_t)l * D * D, Wb, D * D / 4);
        gemm_bf16<<<dim3(D / GBN, BL / GBM), blk, 0, stream>>>(
            Abf, Wb, X, nullptr, X, nullptr, BL, D, D, 0);
        // ---- MLP (SwiGLU) ----
        rmsnorm_bf<<<BL, blk, 0, stream>>>(X, n3 + (size_t)l * D, Hn, D);
        f2b_k<<<(F * D / 4 + 255) / 256, blk, 0, stream>>>(
            Wg + (size_t)l * F * D, Wb, F * D / 4);
        gemm_bf16<<<dim3(F / GBN, BL / GBM), blk, 0, stream>>>(
            Hn, Wb, Gg, nullptr, nullptr, nullptr, BL, F, D, 1);
        f2b_k<<<(F * D / 4 + 255) / 256, blk, 0, stream>>>(
            Wu + (size_t)l * F * D, Wb, F * D / 4);
        gemm_bf16<<<dim3(F / GBN, BL / GBM), blk, 0, stream>>>(
            Hn, Wb, Gg, nullptr, nullptr, Gg, BL, F, D, 1);   // silu(g)*u in place
        f2b_k<<<(D * F / 4 + 255) / 256, blk, 0, stream>>>(
            Wd + (size_t)l * D * F, Wb, D * F / 4);
        gemm_bf16<<<dim3(D / GBN, BL / GBM), blk, 0, stream>>>(
            Gg, Wb, X, nullptr, X, nullptr, BL, D, F, 0);
    }
    rmsnorm_k<<<BL, blk, 0, stream>>>(X, nf, (float*)d_out, D);
}

// Round 2
// 3020.585 us; speedup vs baseline: 2.1524x; 1.4699x over previous
//
#include <hip/hip_runtime.h>
#include <hip/hip_bf16.h>
#include <math.h>

#define N_LAYERS 4
#define NHEADS 16
#define LOOKBACK 128

typedef unsigned short ushort_t;
typedef __attribute__((ext_vector_type(8))) short short8;
typedef __attribute__((ext_vector_type(4))) float f32x4;

__device__ __forceinline__ ushort_t f2bf(float f) {
    union { float f; unsigned int u; } v; v.f = f;
    unsigned int r = (v.u + 0x7FFFu + ((v.u >> 16) & 1u)) >> 16;
    return (ushort_t)r;
}
__device__ __forceinline__ float bf2f(ushort_t s) {
    union { unsigned int u; float f; } v; v.u = ((unsigned int)s) << 16;
    return v.f;
}

// ---------------- block reductions (blockDim == 256, 4 waves) ----------------
__device__ __forceinline__ float blk_sum(float v, volatile float* red) {
#pragma unroll
    for (int o = 32; o > 0; o >>= 1) v += __shfl_down(v, o, 64);
    if ((threadIdx.x & 63) == 0) red[threadIdx.x >> 6] = v;
    __syncthreads();
    float r = red[0] + red[1] + red[2] + red[3];
    __syncthreads();
    return r;
}

// ---------------- fp32 -> bf16 convert ----------------
__global__ __launch_bounds__(256) void f2b_k(const float* __restrict__ in,
                                             ushort_t* __restrict__ out, int n4) {
    int i = blockIdx.x * 256 + threadIdx.x;
    if (i >= n4) return;
    float4 v = *(const float4*)(in + (size_t)i * 4);
    ushort_t* o = out + (size_t)i * 4;
    o[0] = f2bf(v.x); o[1] = f2bf(v.y); o[2] = f2bf(v.z); o[3] = f2bf(v.w);
}

// ---------------- RMSNorm -> bf16 out ----------------
__global__ __launch_bounds__(256) void rmsnorm_bf(const float* __restrict__ x,
                                                  const float* __restrict__ w,
                                                  ushort_t* __restrict__ out, int D) {
    __shared__ float red[4];
    size_t row = blockIdx.x;
    const float* xr = x + row * D;
    float ss = 0.f;
    for (int i = threadIdx.x; i < D; i += 256) { float v = xr[i]; ss += v * v; }
    float tot = blk_sum(ss, red);
    float r = rsqrtf(tot / (float)D + 1e-6f);
    ushort_t* o = out + row * D;
    for (int i = threadIdx.x; i < D; i += 256) o[i] = f2bf(xr[i] * r * w[i]);
}

// ---------------- RMSNorm -> fp32 out (final) ----------------
__global__ __launch_bounds__(256) void rmsnorm_k(const float* __restrict__ x,
                                                 const float* __restrict__ w,
                                                 float* __restrict__ out, int D) {
    __shared__ float red[4];
    size_t row = blockIdx.x;
    const float* xr = x + row * D;
    float ss = 0.f;
    for (int i = threadIdx.x; i < D; i += 256) { float v = xr[i]; ss += v * v; }
    float tot = blk_sum(ss, red);
    float r = rsqrtf(tot / (float)D + 1e-6f);
    float* o = out + row * D;
    for (int i = threadIdx.x; i < D; i += 256) o[i] = xr[i] * r * w[i];
}

// ---------------- bf16 MFMA NT-GEMM (m97 structure) ----------------
// C[m,n] = sum_k A[m,k] * W[n,k]; A,W bf16 row-major; acc fp32.
// 128x128 tile, BK=32, 4 waves, each wave 64x64 via 4x4 mfma_16x16x32.
#define GBM 128
#define GBN 128
#define GBK 32

__global__ __launch_bounds__(256) void gemm_bf16(
    const ushort_t* __restrict__ A, const ushort_t* __restrict__ Bw,
    void* __restrict__ Cout, const float* __restrict__ bias,
    const float* __restrict__ resid, const ushort_t* __restrict__ gate,
    int M, int N, int K, int out_bf16) {
    __shared__ ushort_t As[GBM * GBK];
    __shared__ ushort_t Bs[GBN * GBK];
    int tid = threadIdx.x;
    int wave = tid >> 6, lane = tid & 63;
    int bm = blockIdx.y * GBM, bn = blockIdx.x * GBN;
    int wm = (wave & 1) * 64, wn = (wave >> 1) * 64;
    int r4 = lane >> 2, c4 = lane & 3;        // staging: row-in-16, 16B chunk
    int r = lane & 15, q = lane >> 4;         // mfma lane decomposition

    f32x4 acc[4][4];
#pragma unroll
    for (int i = 0; i < 4; ++i)
#pragma unroll
        for (int j = 0; j < 4; ++j) acc[i][j] = (f32x4){0.f, 0.f, 0.f, 0.f};

    int srow = wave * 16 + r4;
    for (int k0 = 0; k0 < K; k0 += GBK) {
        const ushort_t* Ag = A + (size_t)(bm + srow) * K + k0 + c4 * 8;
        const ushort_t* Bg = Bw + (size_t)(bn + srow) * K + k0 + c4 * 8;
        __builtin_amdgcn_global_load_lds(
            (const __attribute__((address_space(1))) void*)Ag,
            (__attribute__((address_space(3))) void*)&As[wave * 16 * GBK],
            16, 0, 0);
        __builtin_amdgcn_global_load_lds(
            (const __attribute__((address_space(1))) void*)(Ag + (size_t)64 * K),
            (__attribute__((address_space(3))) void*)&As[(64 + wave * 16) * GBK],
            16, 0, 0);
        __builtin_amdgcn_global_load_lds(
            (const __attribute__((address_space(1))) void*)Bg,
            (__attribute__((address_space(3))) void*)&Bs[wave * 16 * GBK],
            16, 0, 0);
        __builtin_amdgcn_global_load_lds(
            (const __attribute__((address_space(1))) void*)(Bg + (size_t)64 * K),
            (__attribute__((address_space(3))) void*)&Bs[(64 + wave * 16) * GBK],
            16, 0, 0);
        __syncthreads();
        short8 af[4], bfr[4];
#pragma unroll
        for (int i = 0; i < 4; ++i)
            af[i] = *(const short8*)&As[(wm + 16 * i + r) * GBK + q * 8];
#pragma unroll
        for (int j = 0; j < 4; ++j)
            bfr[j] = *(const short8*)&Bs[(wn + 16 * j + r) * GBK + q * 8];
#pragma unroll
        for (int i = 0; i < 4; ++i)
#pragma unroll
            for (int j = 0; j < 4; ++j)
                acc[i][j] = __builtin_amdgcn_mfma_f32_16x16x32_bf16(
                    af[i], bfr[j], acc[i][j], 0, 0, 0);
        __syncthreads();
    }
    // epilogue: row = bm+wm+16i+q*4+t, col = bn+wn+16j+r
#pragma unroll
    for (int i = 0; i < 4; ++i) {
#pragma unroll
        for (int j = 0; j < 4; ++j) {
            size_t n = (size_t)(bn + wn + 16 * j + r);
            float bn_v = bias ? bias[n] : 0.f;
#pragma unroll
            for (int t = 0; t < 4; ++t) {
                size_t m = (size_t)(bm + wm + 16 * i + q * 4 + t);
                size_t idx = m * N + n;
                float x = acc[i][j][t] + bn_v;
                if (gate) { float g = bf2f(gate[idx]); x *= g / (1.0f + __expf(-g)); }
                if (resid) x += resid[idx];
                if (out_bf16) ((ushort_t*)Cout)[idx] = f2bf(x);
                else ((float*)Cout)[idx] = x;
            }
        }
    }
}

// ---------------- RoPE in place on bf16 qkv; Q also scaled by 1/sqrt(d) -----
__global__ void rope_k(ushort_t* __restrict__ qkv, int L, int total) {
    int idx = blockIdx.x * 256 + threadIdx.x;
    if (idx >= total) return;
    int d = idx & 31;
    int h = (idx >> 5) & 15;
    int bl = idx >> 9;
    int l = bl % L;
    float inv = powf(10000.0f, -(float)d * (1.0f / 32.0f));
    float f = (float)l * inv;
    float s, c;
    sincosf(f, &s, &c);
    ushort_t* base = qkv + (size_t)bl * 3072 + h * 64 + d;
    float x1 = bf2f(base[0]), x2 = bf2f(base[32]);
    base[0]  = f2bf((x1 * c - x2 * s) * 0.125f);   // Q pre-scaled
    base[32] = f2bf((x2 * c + x1 * s) * 0.125f);
    ushort_t* kb = base + 1024;
    x1 = bf2f(kb[0]); x2 = bf2f(kb[32]);
    kb[0]  = f2bf(x1 * c - x2 * s);
    kb[32] = f2bf(x2 * c + x1 * s);
}

// ---------------- flash self-attention: MFMA, 64q x 64k tiles ---------------
// qkv is bf16, Q already scaled. 4 waves, each owns a 16-row q strip.
// Fragment/C layouts identical to gemm_bf16 (m97-verified):
//   a/b-frag: row = lane&15, k-chunk = (lane>>4)*8
//   C:        row = (lane>>4)*4 + t, col = lane&15
#define AP 72   // padded LDS row (bf16 elems); 144B stride, 16B-aligned

__global__ __launch_bounds__(256) void self_attn_flash(
    const ushort_t* __restrict__ qkv, ushort_t* __restrict__ out, int L) {
    int qt = blockIdx.x, h = blockIdx.y, b = blockIdx.z;
    int q0 = qt * 64;
    __shared__ ushort_t Qs[64 * AP];
    __shared__ ushort_t Ks[64 * AP];
    __shared__ ushort_t VT[64 * AP];   // VT[d][k] = V[k][d]
    __shared__ ushort_t Ps[64 * AP];   // 4 waves x 16 rows of P (bf16)
    int tid = threadIdx.x;
    int wave = tid >> 6, lane = tid & 63;
    int g = lane >> 4, r = lane & 15;
    int lr = tid >> 2, lc = tid & 3;   // staging: row, 16-elem chunk

    // stage Q once (bf16 copy, already scaled)
    {
        const ushort_t* src = qkv + ((size_t)b * L + q0 + lr) * 3072 + h * 64 + lc * 16;
        *(short8*)&Qs[lr * AP + lc * 16]     = *(const short8*)(src);
        *(short8*)&Qs[lr * AP + lc * 16 + 8] = *(const short8*)(src + 8);
    }

    float m[4]    = {-1e30f, -1e30f, -1e30f, -1e30f};
    float lsum[4] = {0.f, 0.f, 0.f, 0.f};
    f32x4 acc[4];
#pragma unroll
    for (int j = 0; j < 4; ++j) acc[j] = (f32x4){0.f, 0.f, 0.f, 0.f};

    for (int kt = 0; kt <= qt; ++kt) {
        int k0 = kt * 64;
        __syncthreads();
        {
            const ushort_t* ksrc = qkv + ((size_t)b * L + k0 + lr) * 3072 + 1024 + h * 64 + lc * 16;
            short8 k0v = *(const short8*)(ksrc);
            short8 k1v = *(const short8*)(ksrc + 8);
            *(short8*)&Ks[lr * AP + lc * 16]     = k0v;
            *(short8*)&Ks[lr * AP + lc * 16 + 8] = k1v;
            const ushort_t* vsrc = ksrc + 1024;
            short8 v0v = *(const short8*)(vsrc);
            short8 v1v = *(const short8*)(vsrc + 8);
#pragma unroll
            for (int i = 0; i < 8; ++i) {
                VT[(lc * 16 + i) * AP + lr]     = (ushort_t)v0v[i];
                VT[(lc * 16 + 8 + i) * AP + lr] = (ushort_t)v1v[i];
            }
        }
        __syncthreads();

        // S = Q_strip(16x64) . K^T(64x64)
        f32x4 s[4];
#pragma unroll
        for (int j = 0; j < 4; ++j) s[j] = (f32x4){0.f, 0.f, 0.f, 0.f};
        short8 aq[2];
#pragma unroll
        for (int c = 0; c < 2; ++c)
            aq[c] = *(const short8*)&Qs[(wave * 16 + r) * AP + c * 32 + g * 8];
#pragma unroll
        for (int j = 0; j < 4; ++j)
#pragma unroll
            for (int c = 0; c < 2; ++c) {
                short8 bk = *(const short8*)&Ks[(16 * j + r) * AP + c * 32 + g * 8];
                s[j] = __builtin_amdgcn_mfma_f32_16x16x32_bf16(aq[c], bk, s[j], 0, 0, 0);
            }

        // causal mask on diagonal tile: k(16j+r) > q(16*wave+4g+t)
        if (kt == qt) {
#pragma unroll
            for (int j = 0; j < 4; ++j)
#pragma unroll
                for (int t = 0; t < 4; ++t)
                    if (16 * j + r > 16 * wave + 4 * g + t) s[j][t] = -1e30f;
        }

        // online softmax; each lane handles rows 4g+t, replicated over r
        float al[4];
#pragma unroll
        for (int t = 0; t < 4; ++t) {
            float rm = fmaxf(fmaxf(s[0][t], s[1][t]), fmaxf(s[2][t], s[3][t]));
#pragma unroll
            for (int o = 8; o > 0; o >>= 1) rm = fmaxf(rm, __shfl_xor(rm, o, 16));
            float mn = fmaxf(m[t], rm);
            al[t] = __expf(m[t] - mn);
            m[t] = mn;
            float rs = 0.f;
#pragma unroll
            for (int j = 0; j < 4; ++j) {
                float p = __expf(s[j][t] - mn);
                s[j][t] = p;
                rs += p;
            }
#pragma unroll
            for (int o = 8; o > 0; o >>= 1) rs += __shfl_xor(rs, o, 16);
            lsum[t] = lsum[t] * al[t] + rs;
        }

        // P -> LDS (bf16, C-layout) then re-read as a-frags. Same-wave only.
        ushort_t* pw = &Ps[wave * 16 * AP];
#pragma unroll
        for (int j = 0; j < 4; ++j)
#pragma unroll
            for (int t = 0; t < 4; ++t)
                pw[(4 * g + t) * AP + 16 * j + r] = f2bf(s[j][t]);
        short8 ap[2];
#pragma unroll
        for (int c = 0; c < 2; ++c)
            ap[c] = *(const short8*)&pw[r * AP + c * 32 + g * 8];

        // rescale O then accumulate P.V via V^T b-frags
#pragma unroll
        for (int j = 0; j < 4; ++j) {
#pragma unroll
            for (int t = 0; t < 4; ++t) acc[j][t] *= al[t];
#pragma unroll
            for (int c = 0; c < 2; ++c) {
                short8 bv = *(const short8*)&VT[(16 * j + r) * AP + c * 32 + g * 8];
                acc[j] = __builtin_amdgcn_mfma_f32_16x16x32_bf16(ap[c], bv, acc[j], 0, 0, 0);
            }
        }
    }

    // epilogue: row = q0+16*wave+4g+t, col = h*64+16j+r
#pragma unroll
    for (int t = 0; t < 4; ++t) {
        float invl = 1.0f / lsum[t];
        size_t orow = ((size_t)b * L + q0 + wave * 16 + 4 * g + t) * 1024 + h * 64;
#pragma unroll
        for (int j = 0; j < 4; ++j)
            out[orow + 16 * j + r] = f2bf(acc[j][t] * invl);
    }
}

// ---------------- cross-attention: MFMA, 64q x 64k tiles --------------------
// qc bf16 [BL,1024] (unscaled); kvc bf16 [B*S,2048] (K cols 0..1023, V 1024..2047).
// Window mask per row: allowed k iff k <= seg && k > seg-LOOKBACK.
// seg_ids sorted along l, S=256 -> tile range [t_lo,t_hi] contiguous, <=4 tiles.
// Fully-masked early tiles produce garbage that is flushed by al=exp(-1e30-m)=0
// when the first real tile arrives (every row's seg-tile is inside the range).
__global__ __launch_bounds__(256) void cross_attn_mfma(
    const ushort_t* __restrict__ qc, const ushort_t* __restrict__ kvc,
    const int* __restrict__ seg_ids, ushort_t* __restrict__ out, int L, int S) {
    int qt = blockIdx.x, h = blockIdx.y, b = blockIdx.z;
    int q0 = qt * 64;
    __shared__ ushort_t Qs[64 * AP];
    __shared__ ushort_t Ks[64 * AP];
    __shared__ ushort_t VT[64 * AP];
    __shared__ ushort_t Ps[64 * AP];
    __shared__ int segs[64];
    __shared__ int bounds[2];
    int tid = threadIdx.x;
    int wave = tid >> 6, lane = tid & 63;
    int g = lane >> 4, r = lane & 15;
    int lr = tid >> 2, lc = tid & 3;

    {
        const ushort_t* src = qc + ((size_t)b * L + q0 + lr) * 1024 + h * 64 + lc * 16;
        *(short8*)&Qs[lr * AP + lc * 16]     = *(const short8*)(src);
        *(short8*)&Qs[lr * AP + lc * 16 + 8] = *(const short8*)(src + 8);
    }
    if (tid < 64) segs[tid] = seg_ids[(size_t)b * L + q0 + tid];
    __syncthreads();
    if (wave == 0) {
        int v = segs[lane];
        int mn = v, mx = v;
#pragma unroll
        for (int o = 32; o > 0; o >>= 1) {
            mn = min(mn, __shfl_down(mn, o, 64));
            mx = max(mx, __shfl_down(mx, o, 64));
        }
        if (lane == 0) { bounds[0] = mn; bounds[1] = mx; }
    }
    int seg_t[4];
#pragma unroll
    for (int t = 0; t < 4; ++t) seg_t[t] = segs[wave * 16 + 4 * g + t];
    short8 aq[2];
#pragma unroll
    for (int c = 0; c < 2; ++c)
        aq[c] = *(const short8*)&Qs[(wave * 16 + r) * AP + c * 32 + g * 8];
    __syncthreads();
    int lo = bounds[0] - (LOOKBACK - 1); if (lo < 0) lo = 0;
    int t_lo = lo >> 6;
    int t_hi = bounds[1] >> 6;

    float m[4]    = {-1e30f, -1e30f, -1e30f, -1e30f};
    float lsum[4] = {0.f, 0.f, 0.f, 0.f};
    f32x4 acc[4];
#pragma unroll
    for (int j = 0; j < 4; ++j) acc[j] = (f32x4){0.f, 0.f, 0.f, 0.f};

    for (int kt = t_lo; kt <= t_hi; ++kt) {
        int k0 = kt * 64;
        __syncthreads();
        {
            const ushort_t* ksrc = kvc + ((size_t)b * S + k0 + lr) * 2048 + h * 64 + lc * 16;
            short8 k0v = *(const short8*)(ksrc);
            short8 k1v = *(const short8*)(ksrc + 8);
            *(short8*)&Ks[lr * AP + lc * 16]     = k0v;
            *(short8*)&Ks[lr * AP + lc * 16 + 8] = k1v;
            const ushort_t* vsrc = ksrc + 1024;
            short8 v0v = *(const short8*)(vsrc);
            short8 v1v = *(const short8*)(vsrc + 8);
#pragma unroll
            for (int i = 0; i < 8; ++i) {
                VT[(lc * 16 + i) * AP + lr]     = (ushort_t)v0v[i];
                VT[(lc * 16 + 8 + i) * AP + lr] = (ushort_t)v1v[i];
            }
        }
        __syncthreads();

        f32x4 s[4];
#pragma unroll
        for (int j = 0; j < 4; ++j) s[j] = (f32x4){0.f, 0.f, 0.f, 0.f};
#pragma unroll
        for (int j = 0; j < 4; ++j)
#pragma unroll
            for (int c = 0; c < 2; ++c) {
                short8 bk = *(const short8*)&Ks[(16 * j + r) * AP + c * 32 + g * 8];
                s[j] = __builtin_amdgcn_mfma_f32_16x16x32_bf16(aq[c], bk, s[j], 0, 0, 0);
            }

        // scale + window mask: k allowed iff k <= seg && k > seg-LOOKBACK
#pragma unroll
        for (int j = 0; j < 4; ++j) {
            int k = k0 + 16 * j + r;
#pragma unroll
            for (int t = 0; t < 4; ++t) {
                float v = s[j][t] * 0.125f;
                if (k > seg_t[t] || k <= seg_t[t] - LOOKBACK) v = -1e30f;
                s[j][t] = v;
            }
        }

        float al[4];
#pragma unroll
        for (int t = 0; t < 4; ++t) {
            float rm = fmaxf(fmaxf(s[0][t], s[1][t]), fmaxf(s[2][t], s[3][t]));
#pragma unroll
            for (int o = 8; o > 0; o >>= 1) rm = fmaxf(rm, __shfl_xor(rm, o, 16));
            float mn = fmaxf(m[t], rm);
            al[t] = __expf(m[t] - mn);
            m[t] = mn;
            float rs = 0.f;
#pragma unroll
            for (int j = 0; j < 4; ++j) {
                float p = __expf(s[j][t] - mn);
                s[j][t] = p;
                rs += p;
            }
#pragma unroll
            for (int o = 8; o > 0; o >>= 1) rs += __shfl_xor(rs, o, 16);
            lsum[t] = lsum[t] * al[t] + rs;
        }

        ushort_t* pw = &Ps[wave * 16 * AP];
#pragma unroll
        for (int j = 0; j < 4; ++j)
#pragma unroll
            for (int t = 0; t < 4; ++t)
                pw[(4 * g + t) * AP + 16 * j + r] = f2bf(s[j][t]);
        short8 ap[2];
#pragma unroll
        for (int c = 0; c < 2; ++c)
            ap[c] = *(const short8*)&pw[r * AP + c * 32 + g * 8];

#pragma unroll
        for (int j = 0; j < 4; ++j) {
#pragma unroll
            for (int t = 0; t < 4; ++t) acc[j][t] *= al[t];
#pragma unroll
            for (int c = 0; c < 2; ++c) {
                short8 bv = *(const short8*)&VT[(16 * j + r) * AP + c * 32 + g * 8];
                acc[j] = __builtin_amdgcn_mfma_f32_16x16x32_bf16(ap[c], bv, acc[j], 0, 0, 0);
            }
        }
    }

#pragma unroll
    for (int t = 0; t < 4; ++t) {
        float invl = 1.0f / lsum[t];
        size_t orow = ((size_t)b * L + q0 + wave * 16 + 4 * g + t) * 1024 + h * 64;
#pragma unroll
        for (int j = 0; j < 4; ++j)
            out[orow + 16 * j + r] = f2bf(acc[j][t] * invl);
    }
}

// ---------------- driver ----------------
extern "C" void kernel_launch(void* const* d_in, const int* in_sizes, int n_in,
                              void* d_out, int out_size, void* d_ws, size_t ws_size,
                              hipStream_t stream) {
    const int B = 2, L = 2048, S = 256, D = 1024, F = 4096;
    const int BL = B * L;
    const float* x_in   = (const float*)d_in[0];
    const float* memory = (const float*)d_in[1];
    const int*   seg    = (const int*)d_in[2];
    const float* Wqkv = (const float*)d_in[3];
    const float* bqkv = (const float*)d_in[4];
    const float* Wo   = (const float*)d_in[5];
    const float* bo   = (const float*)d_in[6];
    const float* Wq_c = (const float*)d_in[7];
    const float* Wkv_c= (const float*)d_in[8];
    const float* Wo_c = (const float*)d_in[9];
    const float* Wg   = (const float*)d_in[10];
    const float* Wu   = (const float*)d_in[11];
    const float* Wd   = (const float*)d_in[12];
    const float* n1   = (const float*)d_in[13];
    const float* n2   = (const float*)d_in[14];
    const float* n3   = (const float*)d_in[15];
    const float* nf   = (const float*)d_in[16];

    char* ws = (char*)d_ws;
    size_t off = 0;
    float* X     = (float*)(ws + off); off += (size_t)BL * D * 4;        // 16 MB
    float* QKV   = (float*)(ws + off); off += (size_t)BL * 3 * D * 4;    // 48 MB (aliases QKVb, Qcb, Gg)
    float* KVC   = (float*)(ws + off); off += (size_t)B * S * 2 * D * 4; // 4 MB
    ushort_t* Hn  = (ushort_t*)(ws + off); off += (size_t)BL * D * 2;    // 8 MB
    ushort_t* Abf = (ushort_t*)(ws + off); off += (size_t)BL * D * 2;    // 8 MB
    ushort_t* Mb  = (ushort_t*)(ws + off); off += (size_t)B * S * D * 2; // 1 MB
    ushort_t* Wb  = (ushort_t*)(ws + off); off += (size_t)F * D * 2;     // 8 MB
    ushort_t* QKVb = (ushort_t*)QKV;    // bf16 view, self-attn phase
    ushort_t* Qcb  = (ushort_t*)QKV;    // bf16 view, cross phase
    ushort_t* KVCb = (ushort_t*)KVC;    // bf16 view, cross phase
    ushort_t* Gg = (ushort_t*)QKV;      // bf16 view, MLP phase

    hipMemcpyAsync(X, x_in, (size_t)BL * D * sizeof(float), hipMemcpyDeviceToDevice, stream);

    dim3 blk(256);
    // memory -> bf16 once
    f2b_k<<<(B * S * D / 4 + 255) / 256, blk, 0, stream>>>(memory, Mb, B * S * D / 4);

    for (int l = 0; l < N_LAYERS; ++l) {
        // ---- self-attention block ----
        rmsnorm_bf<<<BL, blk, 0, stream>>>(X, n1 + (size_t)l * D, Hn, D);
        f2b_k<<<(3 * D * D / 4 + 255) / 256, blk, 0, stream>>>(
            Wqkv + (size_t)l * 3 * D * D, Wb, 3 * D * D / 4);
        gemm_bf16<<<dim3(3 * D / GBN, BL / GBM), blk, 0, stream>>>(
            Hn, Wb, QKVb, bqkv + (size_t)l * 3 * D, nullptr, nullptr, BL, 3 * D, D, 1);
        int total = BL * NHEADS * 32;
        rope_k<<<(total + 255) / 256, blk, 0, stream>>>(QKVb, L, total);
        self_attn_flash<<<dim3(L / 64, NHEADS, B), blk, 0, stream>>>(QKVb, Abf, L);
        f2b_k<<<(D * D / 4 + 255) / 256, blk, 0, stream>>>(
            Wo + (size_t)l * D * D, Wb, D * D / 4);
        gemm_bf16<<<dim3(D / GBN, BL / GBM), blk, 0, stream>>>(
            Abf, Wb, X, bo + (size_t)l * D, X, nullptr, BL, D, D, 0);
        // ---- cross-attention block ----
        rmsnorm_bf<<<BL, blk, 0, stream>>>(X, n2 + (size_t)l * D, Hn, D);
        f2b_k<<<(D * D / 4 + 255) / 256, blk, 0, stream>>>(
            Wq_c + (size_t)l * D * D, Wb, D * D / 4);
        gemm_bf16<<<dim3(D / GBN, BL / GBM), blk, 0, stream>>>(
            Hn, Wb, Qcb, nullptr, nullptr, nullptr, BL, D, D, 1);
        f2b_k<<<(2 * D * D / 4 + 255) / 256, blk, 0, stream>>>(
            Wkv_c + (size_t)l * 2 * D * D, Wb, 2 * D * D / 4);
        gemm_bf16<<<dim3(2 * D / GBN, B * S / GBM), blk, 0, stream>>>(
            Mb, Wb, KVCb, nullptr, nullptr, nullptr, B * S, 2 * D, D, 1);
        cross_attn_mfma<<<dim3(L / 64, NHEADS, B), blk, 0, stream>>>(
            Qcb, KVCb, seg, Abf, L, S);
        f2b_k<<<(D * D / 4 + 255) / 256, blk, 0, stream>>>(
            Wo_c + (size_t)l * D * D, Wb, D * D / 4);
        gemm_bf16<<<dim3(D / GBN, BL / GBM), blk, 0, stream>>>(
            Abf, Wb, X, nullptr, X, nullptr, BL, D, D, 0);
        // ---- MLP (SwiGLU) ----
        rmsnorm_bf<<<BL, blk, 0, stream>>>(X, n3 + (size_t)l * D, Hn, D);
        f2b_k<<<(F * D / 4 + 255) / 256, blk, 0, stream>>>(
            Wg + (size_t)l * F * D, Wb, F * D / 4);
        gemm_bf16<<<dim3(F / GBN, BL / GBM), blk, 0, stream>>>(
            Hn, Wb, Gg, nullptr, nullptr, nullptr, BL, F, D, 1);
        f2b_k<<<(F * D / 4 + 255) / 256, blk, 0, stream>>>(
            Wu + (size_t)l * F * D, Wb, F * D / 4);
        gemm_bf16<<<dim3(F / GBN, BL / GBM), blk, 0, stream>>>(
            Hn, Wb, Gg, nullptr, nullptr, Gg, BL, F, D, 1);   // silu(g)*u in place
        f2b_k<<<(D * F / 4 + 255) / 256, blk, 0, stream>>>(
            Wd + (size_t)l * D * F, Wb, D * F / 4);
        gemm_bf16<<<dim3(D / GBN, BL / GBM), blk, 0, stream>>>(
            Gg, Wb, X, nullptr, X, nullptr, BL, D, F, 0);
    }
    rmsnorm_k<<<BL, blk, 0, stream>>>(X, nf, (float*)d_out, D);
}

// Round 4
// 2864.480 us; speedup vs baseline: 2.2697x; 1.0545x over previous
//
#include <hip/hip_runtime.h>
#include <hip/hip_bf16.h>
#include <math.h>

#define N_LAYERS 4
#define NHEADS 16
#define LOOKBACK 128

typedef unsigned short ushort_t;
typedef __attribute__((ext_vector_type(8))) short short8;
typedef __attribute__((ext_vector_type(4))) float f32x4;

__device__ __forceinline__ ushort_t f2bf(float f) {
    union { float f; unsigned int u; } v; v.f = f;
    unsigned int r = (v.u + 0x7FFFu + ((v.u >> 16) & 1u)) >> 16;
    return (ushort_t)r;
}
__device__ __forceinline__ float bf2f(ushort_t s) {
    union { unsigned int u; float f; } v; v.u = ((unsigned int)s) << 16;
    return v.f;
}

// ---------------- block reductions (blockDim == 256, 4 waves) ----------------
__device__ __forceinline__ float blk_sum(float v, volatile float* red) {
#pragma unroll
    for (int o = 32; o > 0; o >>= 1) v += __shfl_down(v, o, 64);
    if ((threadIdx.x & 63) == 0) red[threadIdx.x >> 6] = v;
    __syncthreads();
    float r = red[0] + red[1] + red[2] + red[3];
    __syncthreads();
    return r;
}

// ---------------- fp32 -> bf16 convert ----------------
__global__ __launch_bounds__(256) void f2b_k(const float* __restrict__ in,
                                             ushort_t* __restrict__ out, int n4) {
    int i = blockIdx.x * 256 + threadIdx.x;
    if (i >= n4) return;
    float4 v = *(const float4*)(in + (size_t)i * 4);
    ushort_t* o = out + (size_t)i * 4;
    o[0] = f2bf(v.x); o[1] = f2bf(v.y); o[2] = f2bf(v.z); o[3] = f2bf(v.w);
}

// ---------------- RMSNorm -> bf16 out ----------------
__global__ __launch_bounds__(256) void rmsnorm_bf(const float* __restrict__ x,
                                                  const float* __restrict__ w,
                                                  ushort_t* __restrict__ out, int D) {
    __shared__ float red[4];
    size_t row = blockIdx.x;
    const float* xr = x + row * D;
    float ss = 0.f;
    for (int i = threadIdx.x; i < D; i += 256) { float v = xr[i]; ss += v * v; }
    float tot = blk_sum(ss, red);
    float r = rsqrtf(tot / (float)D + 1e-6f);
    ushort_t* o = out + row * D;
    for (int i = threadIdx.x; i < D; i += 256) o[i] = f2bf(xr[i] * r * w[i]);
}

// ---------------- RMSNorm -> fp32 out (final) ----------------
__global__ __launch_bounds__(256) void rmsnorm_k(const float* __restrict__ x,
                                                 const float* __restrict__ w,
                                                 float* __restrict__ out, int D) {
    __shared__ float red[4];
    size_t row = blockIdx.x;
    const float* xr = x + row * D;
    float ss = 0.f;
    for (int i = threadIdx.x; i < D; i += 256) { float v = xr[i]; ss += v * v; }
    float tot = blk_sum(ss, red);
    float r = rsqrtf(tot / (float)D + 1e-6f);
    float* o = out + row * D;
    for (int i = threadIdx.x; i < D; i += 256) o[i] = xr[i] * r * w[i];
}

// ---------------- bf16 MFMA NT-GEMM (m97 structure + T1 XCD swizzle) --------
#define GBM 128
#define GBN 128
#define GBK 32

__global__ __launch_bounds__(256) void gemm_bf16(
    const ushort_t* __restrict__ A, const ushort_t* __restrict__ Bw,
    void* __restrict__ Cout, const float* __restrict__ bias,
    const float* __restrict__ resid, const ushort_t* __restrict__ gate,
    int M, int N, int K, int out_bf16) {
    __shared__ ushort_t As[GBM * GBK];
    __shared__ ushort_t Bs[GBN * GBK];
    int tid = threadIdx.x;
    int wave = tid >> 6, lane = tid & 63;
    // bijective XCD swizzle (m204): contiguous grid chunks per XCD
    int nwg = gridDim.x * gridDim.y;
    int wg  = blockIdx.y * gridDim.x + blockIdx.x;
    int qq = nwg >> 3, rr = nwg & 7;
    int xcd = wg & 7, loc = wg >> 3;
    int swz = (xcd < rr ? xcd * (qq + 1) : rr * (qq + 1) + (xcd - rr) * qq) + loc;
    int bm = (swz / gridDim.x) * GBM, bn = (swz % gridDim.x) * GBN;
    int wm = (wave & 1) * 64, wn = (wave >> 1) * 64;
    int r4 = lane >> 2, c4 = lane & 3;        // staging: row-in-16, 16B chunk
    int r = lane & 15, q = lane >> 4;         // mfma lane decomposition

    f32x4 acc[4][4];
#pragma unroll
    for (int i = 0; i < 4; ++i)
#pragma unroll
        for (int j = 0; j < 4; ++j) acc[i][j] = (f32x4){0.f, 0.f, 0.f, 0.f};

    int srow = wave * 16 + r4;
    for (int k0 = 0; k0 < K; k0 += GBK) {
        const ushort_t* Ag = A + (size_t)(bm + srow) * K + k0 + c4 * 8;
        const ushort_t* Bg = Bw + (size_t)(bn + srow) * K + k0 + c4 * 8;
        __builtin_amdgcn_global_load_lds(
            (const __attribute__((address_space(1))) void*)Ag,
            (__attribute__((address_space(3))) void*)&As[wave * 16 * GBK],
            16, 0, 0);
        __builtin_amdgcn_global_load_lds(
            (const __attribute__((address_space(1))) void*)(Ag + (size_t)64 * K),
            (__attribute__((address_space(3))) void*)&As[(64 + wave * 16) * GBK],
            16, 0, 0);
        __builtin_amdgcn_global_load_lds(
            (const __attribute__((address_space(1))) void*)Bg,
            (__attribute__((address_space(3))) void*)&Bs[wave * 16 * GBK],
            16, 0, 0);
        __builtin_amdgcn_global_load_lds(
            (const __attribute__((address_space(1))) void*)(Bg + (size_t)64 * K),
            (__attribute__((address_space(3))) void*)&Bs[(64 + wave * 16) * GBK],
            16, 0, 0);
        __syncthreads();
        short8 af[4], bfr[4];
#pragma unroll
        for (int i = 0; i < 4; ++i)
            af[i] = *(const short8*)&As[(wm + 16 * i + r) * GBK + q * 8];
#pragma unroll
        for (int j = 0; j < 4; ++j)
            bfr[j] = *(const short8*)&Bs[(wn + 16 * j + r) * GBK + q * 8];
#pragma unroll
        for (int i = 0; i < 4; ++i)
#pragma unroll
            for (int j = 0; j < 4; ++j)
                acc[i][j] = __builtin_amdgcn_mfma_f32_16x16x32_bf16(
                    af[i], bfr[j], acc[i][j], 0, 0, 0);
        __syncthreads();
    }
    // epilogue: row = bm+wm+16i+q*4+t, col = bn+wn+16j+r
#pragma unroll
    for (int i = 0; i < 4; ++i) {
#pragma unroll
        for (int j = 0; j < 4; ++j) {
            size_t n = (size_t)(bn + wn + 16 * j + r);
            float bn_v = bias ? bias[n] : 0.f;
#pragma unroll
            for (int t = 0; t < 4; ++t) {
                size_t m = (size_t)(bm + wm + 16 * i + q * 4 + t);
                size_t idx = m * N + n;
                float x = acc[i][j][t] + bn_v;
                if (gate) { float g = bf2f(gate[idx]); x *= g / (1.0f + __expf(-g)); }
                if (resid) x += resid[idx];
                if (out_bf16) ((ushort_t*)Cout)[idx] = f2bf(x);
                else ((float*)Cout)[idx] = x;
            }
        }
    }
}

// ---------------- RoPE in place on bf16 qkv; Q also scaled by 1/sqrt(d) -----
__global__ void rope_k(ushort_t* __restrict__ qkv, int L, int total) {
    int idx = blockIdx.x * 256 + threadIdx.x;
    if (idx >= total) return;
    int d = idx & 31;
    int h = (idx >> 5) & 15;
    int bl = idx >> 9;
    int l = bl % L;
    // 10000^(-d/32) = 2^(-d*log2(10000)/32)
    float inv = exp2f(-(float)d * (13.2877123795f / 32.0f));
    float f = (float)l * inv;
    float s, c;
    sincosf(f, &s, &c);
    ushort_t* base = qkv + (size_t)bl * 3072 + h * 64 + d;
    float x1 = bf2f(base[0]), x2 = bf2f(base[32]);
    base[0]  = f2bf((x1 * c - x2 * s) * 0.125f);   // Q pre-scaled
    base[32] = f2bf((x2 * c + x1 * s) * 0.125f);
    ushort_t* kb = base + 1024;
    x1 = bf2f(kb[0]); x2 = bf2f(kb[32]);
    kb[0]  = f2bf(x1 * c - x2 * s);
    kb[32] = f2bf(x2 * c + x1 * s);
}

// ---------------- flash self-attention: MFMA, 128q x 64k tiles --------------
// 4 waves x two 16-row strips. K/V prefetched to regs (T14). VT/Ps use
// 128B rows + chunk-XOR swizzle: idx(kappa,row) = ((kappa>>3)^f(row))*8+(kappa&7).
#define QB 128

__global__ __launch_bounds__(256) void self_attn_flash(
    const ushort_t* __restrict__ qkv, ushort_t* __restrict__ out, int L) {
    // XCD-aware remap: blocks with same (b,h) map to the same XCD (lin%8).
    int lin = blockIdx.x + gridDim.x * (blockIdx.y + gridDim.y * blockIdx.z);
    int xcd = lin & 7, slot = lin >> 3;
    int qt = slot & 15;               // L/QB = 16
    int grp = xcd + 8 * (slot >> 4);  // 0..31
    int h = grp & 15, b = grp >> 4;
    int q0 = qt * QB;

    __shared__ ushort_t Qs[QB * 72];
    __shared__ ushort_t Ks[64 * 72];
    __shared__ ushort_t VT[64 * 64];   // swizzled, VT[d][k]=V[k][d]
    __shared__ ushort_t Ps[QB * 64];   // swizzled

    int tid = threadIdx.x;
    int wave = tid >> 6, lane = tid & 63;
    int g = lane >> 4, r = lane & 15;
    int lr2 = tid >> 1, lc2 = tid & 1;   // Q staging: row, 32-elem half
    int lr = tid >> 2, lc = tid & 3;     // K/V staging: row, 16-elem chunk

    // stage Q (128 x 64 bf16, already scaled by rope)
    {
        const ushort_t* src = qkv + ((size_t)b * L + q0 + lr2) * 3072 + h * 64 + lc2 * 32;
        ushort_t* dst = &Qs[lr2 * 72 + lc2 * 32];
        *(short8*)(dst)      = *(const short8*)(src);
        *(short8*)(dst + 8)  = *(const short8*)(src + 8);
        *(short8*)(dst + 16) = *(const short8*)(src + 16);
        *(short8*)(dst + 24) = *(const short8*)(src + 24);
    }
    __syncthreads();
    short8 aq[2][2];
#pragma unroll
    for (int s = 0; s < 2; ++s)
#pragma unroll
        for (int c = 0; c < 2; ++c)
            aq[s][c] = *(const short8*)&Qs[(wave * 32 + s * 16 + r) * 72 + c * 32 + g * 8];

    // prefetch kt=0 K/V into regs
    const ushort_t* kvbase = qkv + ((size_t)b * L + lr) * 3072 + 1024 + h * 64 + lc * 16;
    short8 kreg0 = *(const short8*)(kvbase);
    short8 kreg1 = *(const short8*)(kvbase + 8);
    short8 vreg0 = *(const short8*)(kvbase + 1024);
    short8 vreg1 = *(const short8*)(kvbase + 1032);

    float m[2][4], lsum[2][4];
    f32x4 acc[2][4];
#pragma unroll
    for (int s = 0; s < 2; ++s)
#pragma unroll
        for (int t = 0; t < 4; ++t) { m[s][t] = -1e30f; lsum[s][t] = 0.f; }
#pragma unroll
    for (int s = 0; s < 2; ++s)
#pragma unroll
        for (int j = 0; j < 4; ++j) acc[s][j] = (f32x4){0.f, 0.f, 0.f, 0.f};

    int ktmax = 2 * qt + 1;
    for (int kt = 0; kt <= ktmax; ++kt) {
        __syncthreads();   // prev compute done reading Ks/VT
        // write staged regs to LDS
        *(short8*)&Ks[lr * 72 + lc * 16]     = kreg0;
        *(short8*)&Ks[lr * 72 + lc * 16 + 8] = kreg1;
#pragma unroll
        for (int i = 0; i < 8; ++i) {
            int row0 = lc * 16 + i;
            int f0 = (row0 & 7) ^ ((row0 >> 4) & 3);
            VT[row0 * 64 + (((lr >> 3) ^ f0) << 3) + (lr & 7)] = (ushort_t)vreg0[i];
            int row1 = row0 + 8;
            int f1 = (row1 & 7) ^ ((row1 >> 4) & 3);
            VT[row1 * 64 + (((lr >> 3) ^ f1) << 3) + (lr & 7)] = (ushort_t)vreg1[i];
        }
        // prefetch next tile (latency hides under compute below)
        if (kt < ktmax) {
            const ushort_t* p = kvbase + (size_t)(kt + 1) * 64 * 3072;
            kreg0 = *(const short8*)(p);
            kreg1 = *(const short8*)(p + 8);
            vreg0 = *(const short8*)(p + 1024);
            vreg1 = *(const short8*)(p + 1032);
        }
        __syncthreads();

        int k0 = kt * 64;
        // S = Q(2x16x64) . K^T : 8 LDS reads feed 16 MFMAs
        f32x4 s2[2][4];
#pragma unroll
        for (int s = 0; s < 2; ++s)
#pragma unroll
            for (int j = 0; j < 4; ++j) s2[s][j] = (f32x4){0.f, 0.f, 0.f, 0.f};
#pragma unroll
        for (int j = 0; j < 4; ++j)
#pragma unroll
            for (int c = 0; c < 2; ++c) {
                short8 bk = *(const short8*)&Ks[(16 * j + r) * 72 + c * 32 + g * 8];
                s2[0][j] = __builtin_amdgcn_mfma_f32_16x16x32_bf16(aq[0][c], bk, s2[0][j], 0, 0, 0);
                s2[1][j] = __builtin_amdgcn_mfma_f32_16x16x32_bf16(aq[1][c], bk, s2[1][j], 0, 0, 0);
            }

        // causal mask only on the top two tiles
        if (kt >= ktmax - 1) {
#pragma unroll
            for (int s = 0; s < 2; ++s)
#pragma unroll
                for (int j = 0; j < 4; ++j) {
                    int k = k0 + 16 * j + r;
#pragma unroll
                    for (int t = 0; t < 4; ++t)
                        if (k > q0 + wave * 32 + s * 16 + 4 * g + t) s2[s][j][t] = -1e30f;
                }
        }

        // online softmax per strip
        float al[2][4];
#pragma unroll
        for (int s = 0; s < 2; ++s)
#pragma unroll
            for (int t = 0; t < 4; ++t) {
                float rm = fmaxf(fmaxf(s2[s][0][t], s2[s][1][t]), fmaxf(s2[s][2][t], s2[s][3][t]));
#pragma unroll
                for (int o = 8; o > 0; o >>= 1) rm = fmaxf(rm, __shfl_xor(rm, o, 16));
                float mn = fmaxf(m[s][t], rm);
                al[s][t] = __expf(m[s][t] - mn);
                m[s][t] = mn;
                float rs = 0.f;
#pragma unroll
                for (int j = 0; j < 4; ++j) {
                    float p = __expf(s2[s][j][t] - mn);
                    s2[s][j][t] = p;
                    rs += p;
                }
#pragma unroll
                for (int o = 8; o > 0; o >>= 1) rs += __shfl_xor(rs, o, 16);
                lsum[s][t] = lsum[s][t] * al[s][t] + rs;
            }

        // P -> LDS (swizzled), re-read as a-frags (same wave only)
#pragma unroll
        for (int s = 0; s < 2; ++s)
#pragma unroll
            for (int j = 0; j < 4; ++j)
#pragma unroll
                for (int t = 0; t < 4; ++t) {
                    int row = wave * 32 + s * 16 + 4 * g + t;
                    int f = (row >> 1) & 7;
                    Ps[row * 64 + (((2 * j + (r >> 3)) ^ f) << 3) + (r & 7)] = f2bf(s2[s][j][t]);
                }
        short8 ap[2][2];
#pragma unroll
        for (int s = 0; s < 2; ++s) {
            int row = wave * 32 + s * 16 + r;
            int f = (row >> 1) & 7;
#pragma unroll
            for (int c = 0; c < 2; ++c)
                ap[s][c] = *(const short8*)&Ps[row * 64 + (((4 * c + g) ^ f) << 3)];
        }

        // rescale O, then PV: 8 LDS reads feed 16 MFMAs
#pragma unroll
        for (int s = 0; s < 2; ++s)
#pragma unroll
            for (int j = 0; j < 4; ++j)
#pragma unroll
                for (int t = 0; t < 4; ++t) acc[s][j][t] *= al[s][t];
#pragma unroll
        for (int j = 0; j < 4; ++j)
#pragma unroll
            for (int c = 0; c < 2; ++c) {
                int row = 16 * j + r;
                int ch = (4 * c + g) ^ (r & 7) ^ j;
                short8 bv = *(const short8*)&VT[row * 64 + (ch << 3)];
                acc[0][j] = __builtin_amdgcn_mfma_f32_16x16x32_bf16(ap[0][c], bv, acc[0][j], 0, 0, 0);
                acc[1][j] = __builtin_amdgcn_mfma_f32_16x16x32_bf16(ap[1][c], bv, acc[1][j], 0, 0, 0);
            }
    }

    // epilogue: row = q0+wave*32+s*16+4g+t, col = h*64+16j+r
#pragma unroll
    for (int s = 0; s < 2; ++s)
#pragma unroll
        for (int t = 0; t < 4; ++t) {
            float invl = 1.0f / lsum[s][t];
            size_t orow = ((size_t)b * L + q0 + wave * 32 + s * 16 + 4 * g + t) * 1024 + h * 64;
#pragma unroll
            for (int j = 0; j < 4; ++j)
                out[orow + 16 * j + r] = f2bf(acc[s][j][t] * invl);
        }
}

// ---------------- cross-attention: MFMA, 64q x 64k tiles --------------------
#define AP 72

__global__ __launch_bounds__(256) void cross_attn_mfma(
    const ushort_t* __restrict__ qc, const ushort_t* __restrict__ kvc,
    const int* __restrict__ seg_ids, ushort_t* __restrict__ out, int L, int S) {
    int qt = blockIdx.x, h = blockIdx.y, b = blockIdx.z;
    int q0 = qt * 64;
    __shared__ ushort_t Qs[64 * AP];
    __shared__ ushort_t Ks[64 * AP];
    __shared__ ushort_t VT[64 * AP];
    __shared__ ushort_t Ps[64 * AP];
    __shared__ int segs[64];
    __shared__ int bounds[2];
    int tid = threadIdx.x;
    int wave = tid >> 6, lane = tid & 63;
    int g = lane >> 4, r = lane & 15;
    int lr = tid >> 2, lc = tid & 3;

    {
        const ushort_t* src = qc + ((size_t)b * L + q0 + lr) * 1024 + h * 64 + lc * 16;
        *(short8*)&Qs[lr * AP + lc * 16]     = *(const short8*)(src);
        *(short8*)&Qs[lr * AP + lc * 16 + 8] = *(const short8*)(src + 8);
    }
    if (tid < 64) segs[tid] = seg_ids[(size_t)b * L + q0 + tid];
    __syncthreads();
    if (wave == 0) {
        int v = segs[lane];
        int mn = v, mx = v;
#pragma unroll
        for (int o = 32; o > 0; o >>= 1) {
            mn = min(mn, __shfl_down(mn, o, 64));
            mx = max(mx, __shfl_down(mx, o, 64));
        }
        if (lane == 0) { bounds[0] = mn; bounds[1] = mx; }
    }
    int seg_t[4];
#pragma unroll
    for (int t = 0; t < 4; ++t) seg_t[t] = segs[wave * 16 + 4 * g + t];
    short8 aq[2];
#pragma unroll
    for (int c = 0; c < 2; ++c)
        aq[c] = *(const short8*)&Qs[(wave * 16 + r) * AP + c * 32 + g * 8];
    __syncthreads();
    int lo = bounds[0] - (LOOKBACK - 1); if (lo < 0) lo = 0;
    int t_lo = lo >> 6;
    int t_hi = bounds[1] >> 6;

    float m[4]    = {-1e30f, -1e30f, -1e30f, -1e30f};
    float lsum[4] = {0.f, 0.f, 0.f, 0.f};
    f32x4 acc[4];
#pragma unroll
    for (int j = 0; j < 4; ++j) acc[j] = (f32x4){0.f, 0.f, 0.f, 0.f};

    for (int kt = t_lo; kt <= t_hi; ++kt) {
        int k0 = kt * 64;
        __syncthreads();
        {
            const ushort_t* ksrc = kvc + ((size_t)b * S + k0 + lr) * 2048 + h * 64 + lc * 16;
            short8 k0v = *(const short8*)(ksrc);
            short8 k1v = *(const short8*)(ksrc + 8);
            *(short8*)&Ks[lr * AP + lc * 16]     = k0v;
            *(short8*)&Ks[lr * AP + lc * 16 + 8] = k1v;
            const ushort_t* vsrc = ksrc + 1024;
            short8 v0v = *(const short8*)(vsrc);
            short8 v1v = *(const short8*)(vsrc + 8);
#pragma unroll
            for (int i = 0; i < 8; ++i) {
                VT[(lc * 16 + i) * AP + lr]     = (ushort_t)v0v[i];
                VT[(lc * 16 + 8 + i) * AP + lr] = (ushort_t)v1v[i];
            }
        }
        __syncthreads();

        f32x4 s[4];
#pragma unroll
        for (int j = 0; j < 4; ++j) s[j] = (f32x4){0.f, 0.f, 0.f, 0.f};
#pragma unroll
        for (int j = 0; j < 4; ++j)
#pragma unroll
            for (int c = 0; c < 2; ++c) {
                short8 bk = *(const short8*)&Ks[(16 * j + r) * AP + c * 32 + g * 8];
                s[j] = __builtin_amdgcn_mfma_f32_16x16x32_bf16(aq[c], bk, s[j], 0, 0, 0);
            }

        // scale + window mask: k allowed iff k <= seg && k > seg-LOOKBACK
#pragma unroll
        for (int j = 0; j < 4; ++j) {
            int k = k0 + 16 * j + r;
#pragma unroll
            for (int t = 0; t < 4; ++t) {
                float v = s[j][t] * 0.125f;
                if (k > seg_t[t] || k <= seg_t[t] - LOOKBACK) v = -1e30f;
                s[j][t] = v;
            }
        }

        float al[4];
#pragma unroll
        for (int t = 0; t < 4; ++t) {
            float rm = fmaxf(fmaxf(s[0][t], s[1][t]), fmaxf(s[2][t], s[3][t]));
#pragma unroll
            for (int o = 8; o > 0; o >>= 1) rm = fmaxf(rm, __shfl_xor(rm, o, 16));
            float mn = fmaxf(m[t], rm);
            al[t] = __expf(m[t] - mn);
            m[t] = mn;
            float rs = 0.f;
#pragma unroll
            for (int j = 0; j < 4; ++j) {
                float p = __expf(s[j][t] - mn);
                s[j][t] = p;
                rs += p;
            }
#pragma unroll
            for (int o = 8; o > 0; o >>= 1) rs += __shfl_xor(rs, o, 16);
            lsum[t] = lsum[t] * al[t] + rs;
        }

        ushort_t* pw = &Ps[wave * 16 * AP];
#pragma unroll
        for (int j = 0; j < 4; ++j)
#pragma unroll
            for (int t = 0; t < 4; ++t)
                pw[(4 * g + t) * AP + 16 * j + r] = f2bf(s[j][t]);
        short8 ap[2];
#pragma unroll
        for (int c = 0; c < 2; ++c)
            ap[c] = *(const short8*)&pw[r * AP + c * 32 + g * 8];

#pragma unroll
        for (int j = 0; j < 4; ++j) {
#pragma unroll
            for (int t = 0; t < 4; ++t) acc[j][t] *= al[t];
#pragma unroll
            for (int c = 0; c < 2; ++c) {
                short8 bv = *(const short8*)&VT[(16 * j + r) * AP + c * 32 + g * 8];
                acc[j] = __builtin_amdgcn_mfma_f32_16x16x32_bf16(ap[c], bv, acc[j], 0, 0, 0);
            }
        }
    }

#pragma unroll
    for (int t = 0; t < 4; ++t) {
        float invl = 1.0f / lsum[t];
        size_t orow = ((size_t)b * L + q0 + wave * 16 + 4 * g + t) * 1024 + h * 64;
#pragma unroll
        for (int j = 0; j < 4; ++j)
            out[orow + 16 * j + r] = f2bf(acc[j][t] * invl);
    }
}

// ---------------- driver ----------------
extern "C" void kernel_launch(void* const* d_in, const int* in_sizes, int n_in,
                              void* d_out, int out_size, void* d_ws, size_t ws_size,
                              hipStream_t stream) {
    const int B = 2, L = 2048, S = 256, D = 1024, F = 4096;
    const int BL = B * L;
    const float* x_in   = (const float*)d_in[0];
    const float* memory = (const float*)d_in[1];
    const int*   seg    = (const int*)d_in[2];
    const float* Wqkv = (const float*)d_in[3];
    const float* bqkv = (const float*)d_in[4];
    const float* Wo   = (const float*)d_in[5];
    const float* bo   = (const float*)d_in[6];
    const float* Wq_c = (const float*)d_in[7];
    const float* Wkv_c= (const float*)d_in[8];
    const float* Wo_c = (const float*)d_in[9];
    const float* Wg   = (const float*)d_in[10];
    const float* Wu   = (const float*)d_in[11];
    const float* Wd   = (const float*)d_in[12];
    const float* n1   = (const float*)d_in[13];
    const float* n2   = (const float*)d_in[14];
    const float* n3   = (const float*)d_in[15];
    const float* nf   = (const float*)d_in[16];

    char* ws = (char*)d_ws;
    size_t off = 0;
    float* X     = (float*)(ws + off); off += (size_t)BL * D * 4;        // 16 MB
    float* QKV   = (float*)(ws + off); off += (size_t)BL * 3 * D * 4;    // 48 MB (aliases QKVb, Qcb, Gg)
    float* KVC   = (float*)(ws + off); off += (size_t)B * S * 2 * D * 4; // 4 MB
    ushort_t* Hn  = (ushort_t*)(ws + off); off += (size_t)BL * D * 2;    // 8 MB
    ushort_t* Abf = (ushort_t*)(ws + off); off += (size_t)BL * D * 2;    // 8 MB
    ushort_t* Mb  = (ushort_t*)(ws + off); off += (size_t)B * S * D * 2; // 1 MB
    ushort_t* Wb  = (ushort_t*)(ws + off); off += (size_t)F * D * 2;     // 8 MB
    ushort_t* QKVb = (ushort_t*)QKV;    // bf16 view, self-attn phase
    ushort_t* Qcb  = (ushort_t*)QKV;    // bf16 view, cross phase
    ushort_t* KVCb = (ushort_t*)KVC;    // bf16 view, cross phase
    ushort_t* Gg = (ushort_t*)QKV;      // bf16 view, MLP phase

    hipMemcpyAsync(X, x_in, (size_t)BL * D * sizeof(float), hipMemcpyDeviceToDevice, stream);

    dim3 blk(256);
    // memory -> bf16 once
    f2b_k<<<(B * S * D / 4 + 255) / 256, blk, 0, stream>>>(memory, Mb, B * S * D / 4);

    for (int l = 0; l < N_LAYERS; ++l) {
        // ---- self-attention block ----
        rmsnorm_bf<<<BL, blk, 0, stream>>>(X, n1 + (size_t)l * D, Hn, D);
        f2b_k<<<(3 * D * D / 4 + 255) / 256, blk, 0, stream>>>(
            Wqkv + (size_t)l * 3 * D * D, Wb, 3 * D * D / 4);
        gemm_bf16<<<dim3(3 * D / GBN, BL / GBM), blk, 0, stream>>>(
            Hn, Wb, QKVb, bqkv + (size_t)l * 3 * D, nullptr, nullptr, BL, 3 * D, D, 1);
        int total = BL * NHEADS * 32;
        rope_k<<<(total + 255) / 256, blk, 0, stream>>>(QKVb, L, total);
        self_attn_flash<<<dim3(L / QB, NHEADS, B), blk, 0, stream>>>(QKVb, Abf, L);
        f2b_k<<<(D * D / 4 + 255) / 256, blk, 0, stream>>>(
            Wo + (size_t)l * D * D, Wb, D * D / 4);
        gemm_bf16<<<dim3(D / GBN, BL / GBM), blk, 0, stream>>>(
            Abf, Wb, X, bo + (size_t)l * D, X, nullptr, BL, D, D, 0);
        // ---- cross-attention block ----
        rmsnorm_bf<<<BL, blk, 0, stream>>>(X, n2 + (size_t)l * D, Hn, D);
        f2b_k<<<(D * D / 4 + 255) / 256, blk, 0, stream>>>(
            Wq_c + (size_t)l * D * D, Wb, D * D / 4);
        gemm_bf16<<<dim3(D / GBN, BL / GBM), blk, 0, stream>>>(
            Hn, Wb, Qcb, nullptr, nullptr, nullptr, BL, D, D, 1);
        f2b_k<<<(2 * D * D / 4 + 255) / 256, blk, 0, stream>>>(
            Wkv_c + (size_t)l * 2 * D * D, Wb, 2 * D * D / 4);
        gemm_bf16<<<dim3(2 * D / GBN, B * S / GBM), blk, 0, stream>>>(
            Mb, Wb, KVCb, nullptr, nullptr, nullptr, B * S, 2 * D, D, 1);
        cross_attn_mfma<<<dim3(L / 64, NHEADS, B), blk, 0, stream>>>(
            Qcb, KVCb, seg, Abf, L, S);
        f2b_k<<<(D * D / 4 + 255) / 256, blk, 0, stream>>>(
            Wo_c + (size_t)l * D * D, Wb, D * D / 4);
        gemm_bf16<<<dim3(D / GBN, BL / GBM), blk, 0, stream>>>(
            Abf, Wb, X, nullptr, X, nullptr, BL, D, D, 0);
        // ---- MLP (SwiGLU) ----
        rmsnorm_bf<<<BL, blk, 0, stream>>>(X, n3 + (size_t)l * D, Hn, D);
        f2b_k<<<(F * D / 4 + 255) / 256, blk, 0, stream>>>(
            Wg + (size_t)l * F * D, Wb, F * D / 4);
        gemm_bf16<<<dim3(F / GBN, BL / GBM), blk, 0, stream>>>(
            Hn, Wb, Gg, nullptr, nullptr, nullptr, BL, F, D, 1);
        f2b_k<<<(F * D / 4 + 255) / 256, blk, 0, stream>>>(
            Wu + (size_t)l * F * D, Wb, F * D / 4);
        gemm_bf16<<<dim3(F / GBN, BL / GBM), blk, 0, stream>>>(
            Hn, Wb, Gg, nullptr, nullptr, Gg, BL, F, D, 1);   // silu(g)*u in place
        f2b_k<<<(D * F / 4 + 255) / 256, blk, 0, stream>>>(
            Wd + (size_t)l * D * F, Wb, D * F / 4);
        gemm_bf16<<<dim3(D / GBN, BL / GBM), blk, 0, stream>>>(
            Gg, Wb, X, nullptr, X, nullptr, BL, D, F, 0);
    }
    rmsnorm_k<<<BL, blk, 0, stream>>>(X, nf, (float*)d_out, D);
}

// Round 5
// 2718.493 us; speedup vs baseline: 2.3916x; 1.0537x over previous
//
#include <hip/hip_runtime.h>
#include <hip/hip_bf16.h>
#include <math.h>

#define N_LAYERS 4
#define NHEADS 16
#define LOOKBACK 128

typedef unsigned short ushort_t;
typedef __attribute__((ext_vector_type(8))) short short8;
typedef __attribute__((ext_vector_type(4))) float f32x4;

__device__ __forceinline__ ushort_t f2bf(float f) {
    union { float f; unsigned int u; } v; v.f = f;
    unsigned int r = (v.u + 0x7FFFu + ((v.u >> 16) & 1u)) >> 16;
    return (ushort_t)r;
}
__device__ __forceinline__ float bf2f(ushort_t s) {
    union { unsigned int u; float f; } v; v.u = ((unsigned int)s) << 16;
    return v.f;
}

// ---------------- block reductions (blockDim == 256, 4 waves) ----------------
__device__ __forceinline__ float blk_sum(float v, volatile float* red) {
#pragma unroll
    for (int o = 32; o > 0; o >>= 1) v += __shfl_down(v, o, 64);
    if ((threadIdx.x & 63) == 0) red[threadIdx.x >> 6] = v;
    __syncthreads();
    float r = red[0] + red[1] + red[2] + red[3];
    __syncthreads();
    return r;
}

// ---------------- fp32 -> bf16 convert ----------------
__global__ __launch_bounds__(256) void f2b_k(const float* __restrict__ in,
                                             ushort_t* __restrict__ out, int n4) {
    int i = blockIdx.x * 256 + threadIdx.x;
    if (i >= n4) return;
    float4 v = *(const float4*)(in + (size_t)i * 4);
    ushort_t* o = out + (size_t)i * 4;
    o[0] = f2bf(v.x); o[1] = f2bf(v.y); o[2] = f2bf(v.z); o[3] = f2bf(v.w);
}

// ---------------- RMSNorm -> bf16 out ----------------
__global__ __launch_bounds__(256) void rmsnorm_bf(const float* __restrict__ x,
                                                  const float* __restrict__ w,
                                                  ushort_t* __restrict__ out, int D) {
    __shared__ float red[4];
    size_t row = blockIdx.x;
    const float* xr = x + row * D;
    float ss = 0.f;
    for (int i = threadIdx.x; i < D; i += 256) { float v = xr[i]; ss += v * v; }
    float tot = blk_sum(ss, red);
    float r = rsqrtf(tot / (float)D + 1e-6f);
    ushort_t* o = out + row * D;
    for (int i = threadIdx.x; i < D; i += 256) o[i] = f2bf(xr[i] * r * w[i]);
}

// ---------------- RMSNorm -> fp32 out (final) ----------------
__global__ __launch_bounds__(256) void rmsnorm_k(const float* __restrict__ x,
                                                 const float* __restrict__ w,
                                                 float* __restrict__ out, int D) {
    __shared__ float red[4];
    size_t row = blockIdx.x;
    const float* xr = x + row * D;
    float ss = 0.f;
    for (int i = threadIdx.x; i < D; i += 256) { float v = xr[i]; ss += v * v; }
    float tot = blk_sum(ss, red);
    float r = rsqrtf(tot / (float)D + 1e-6f);
    float* o = out + row * D;
    for (int i = threadIdx.x; i < D; i += 256) o[i] = xr[i] * r * w[i];
}

// ---------------- bf16 MFMA NT-GEMM: dbuf LDS + counted vmcnt (T3/T4) -------
#define GBM 128
#define GBN 128
#define GBK 32

#define STAGE_GEMM(kk, buf) do {                                               \
    const ushort_t* Ag_ = A + (size_t)(bm + srow) * K + (kk) + c4 * 8;         \
    const ushort_t* Bg_ = Bw + (size_t)(bn + srow) * K + (kk) + c4 * 8;        \
    __builtin_amdgcn_global_load_lds(                                          \
        (const __attribute__((address_space(1))) void*)Ag_,                    \
        (__attribute__((address_space(3))) void*)&As[buf][wave * 16 * GBK],    \
        16, 0, 0);                                                             \
    __builtin_amdgcn_global_load_lds(                                          \
        (const __attribute__((address_space(1))) void*)(Ag_ + (size_t)64 * K), \
        (__attribute__((address_space(3))) void*)&As[buf][(64 + wave * 16) * GBK], \
        16, 0, 0);                                                             \
    __builtin_amdgcn_global_load_lds(                                          \
        (const __attribute__((address_space(1))) void*)Bg_,                    \
        (__attribute__((address_space(3))) void*)&Bs[buf][wave * 16 * GBK],    \
        16, 0, 0);                                                             \
    __builtin_amdgcn_global_load_lds(                                          \
        (const __attribute__((address_space(1))) void*)(Bg_ + (size_t)64 * K), \
        (__attribute__((address_space(3))) void*)&Bs[buf][(64 + wave * 16) * GBK], \
        16, 0, 0);                                                             \
} while (0)

__global__ __launch_bounds__(256) void gemm_bf16(
    const ushort_t* __restrict__ A, const ushort_t* __restrict__ Bw,
    void* __restrict__ Cout, const float* __restrict__ bias,
    const float* __restrict__ resid, const ushort_t* __restrict__ gate,
    int M, int N, int K, int out_bf16) {
    __shared__ ushort_t As[2][GBM * GBK];
    __shared__ ushort_t Bs[2][GBN * GBK];
    int tid = threadIdx.x;
    int wave = tid >> 6, lane = tid & 63;
    // bijective XCD swizzle (m204): contiguous grid chunks per XCD
    int nwg = gridDim.x * gridDim.y;
    int wg  = blockIdx.y * gridDim.x + blockIdx.x;
    int qq = nwg >> 3, rr = nwg & 7;
    int xcd = wg & 7, loc = wg >> 3;
    int swz = (xcd < rr ? xcd * (qq + 1) : rr * (qq + 1) + (xcd - rr) * qq) + loc;
    int bm = (swz / gridDim.x) * GBM, bn = (swz % gridDim.x) * GBN;
    int wm = (wave & 1) * 64, wn = (wave >> 1) * 64;
    int r4 = lane >> 2, c4 = lane & 3;        // staging: row-in-16, 16B chunk
    int r = lane & 15, q = lane >> 4;         // mfma lane decomposition

    f32x4 acc[4][4];
#pragma unroll
    for (int i = 0; i < 4; ++i)
#pragma unroll
        for (int j = 0; j < 4; ++j) acc[i][j] = (f32x4){0.f, 0.f, 0.f, 0.f};

    int srow = wave * 16 + r4;
    int nt = K / GBK;
    STAGE_GEMM(0, 0);
    for (int t = 0; t < nt; ++t) {
        int cur = t & 1;
        if (t + 1 < nt) {
            STAGE_GEMM((t + 1) * GBK, cur ^ 1);
            asm volatile("s_waitcnt vmcnt(4)" ::: "memory");   // tile-t loads landed
        } else {
            asm volatile("s_waitcnt vmcnt(0)" ::: "memory");
        }
        __builtin_amdgcn_s_barrier();          // all waves' tile-t loads landed
        __builtin_amdgcn_sched_barrier(0);
        short8 af[4], bfr[4];
#pragma unroll
        for (int i = 0; i < 4; ++i)
            af[i] = *(const short8*)&As[cur][(wm + 16 * i + r) * GBK + q * 8];
#pragma unroll
        for (int j = 0; j < 4; ++j)
            bfr[j] = *(const short8*)&Bs[cur][(wn + 16 * j + r) * GBK + q * 8];
#pragma unroll
        for (int i = 0; i < 4; ++i)
#pragma unroll
            for (int j = 0; j < 4; ++j)
                acc[i][j] = __builtin_amdgcn_mfma_f32_16x16x32_bf16(
                    af[i], bfr[j], acc[i][j], 0, 0, 0);
        __builtin_amdgcn_s_barrier();          // release buf[cur] for overwrite at t+2
        __builtin_amdgcn_sched_barrier(0);
    }
    // epilogue: row = bm+wm+16i+q*4+t, col = bn+wn+16j+r
#pragma unroll
    for (int i = 0; i < 4; ++i) {
#pragma unroll
        for (int j = 0; j < 4; ++j) {
            size_t n = (size_t)(bn + wn + 16 * j + r);
            float bn_v = bias ? bias[n] : 0.f;
#pragma unroll
            for (int t = 0; t < 4; ++t) {
                size_t m = (size_t)(bm + wm + 16 * i + q * 4 + t);
                size_t idx = m * N + n;
                float x = acc[i][j][t] + bn_v;
                if (gate) { float g = bf2f(gate[idx]); x *= g / (1.0f + __expf(-g)); }
                if (resid) x += resid[idx];
                if (out_bf16) ((ushort_t*)Cout)[idx] = f2bf(x);
                else ((float*)Cout)[idx] = x;
            }
        }
    }
}

// ---------------- RoPE in place on bf16 qkv; Q also scaled by 1/sqrt(d) -----
__global__ void rope_k(ushort_t* __restrict__ qkv, int L, int total) {
    int idx = blockIdx.x * 256 + threadIdx.x;
    if (idx >= total) return;
    int d = idx & 31;
    int h = (idx >> 5) & 15;
    int bl = idx >> 9;
    int l = bl % L;
    float inv = exp2f(-(float)d * (13.2877123795f / 32.0f));
    float f = (float)l * inv;
    float s, c;
    sincosf(f, &s, &c);
    ushort_t* base = qkv + (size_t)bl * 3072 + h * 64 + d;
    float x1 = bf2f(base[0]), x2 = bf2f(base[32]);
    base[0]  = f2bf((x1 * c - x2 * s) * 0.125f);   // Q pre-scaled
    base[32] = f2bf((x2 * c + x1 * s) * 0.125f);
    ushort_t* kb = base + 1024;
    x1 = bf2f(kb[0]); x2 = bf2f(kb[32]);
    kb[0]  = f2bf(x1 * c - x2 * s);
    kb[32] = f2bf(x2 * c + x1 * s);
}

// ---------------- flash self-attention: MFMA, 128q x 64k tiles --------------
// 4 waves x two 16-row strips. K/V double-buffered in LDS, ONE raw barrier
// per tile (ds_write -> lgkmcnt(0) -> s_barrier); prefetch issued after the
// barrier so it is never drained. VT/Ps chunk-XOR swizzled (128B rows).
#define QB 128

__global__ __launch_bounds__(256) void self_attn_flash(
    const ushort_t* __restrict__ qkv, ushort_t* __restrict__ out, int L) {
    // XCD-aware remap: blocks with same (b,h) map to the same XCD (lin%8).
    int lin = blockIdx.x + gridDim.x * (blockIdx.y + gridDim.y * blockIdx.z);
    int xcd = lin & 7, slot = lin >> 3;
    int qt = slot & 15;               // L/QB = 16
    int grp = xcd + 8 * (slot >> 4);  // 0..31
    int h = grp & 15, b = grp >> 4;
    int q0 = qt * QB;

    __shared__ ushort_t Qs[QB * 72];
    __shared__ ushort_t Ks[2][64 * 72];
    __shared__ ushort_t VT[2][64 * 64];   // swizzled, VT[d][k]=V[k][d]
    __shared__ ushort_t Ps[QB * 64];      // swizzled, per-wave rows

    int tid = threadIdx.x;
    int wave = tid >> 6, lane = tid & 63;
    int g = lane >> 4, r = lane & 15;
    int lr2 = tid >> 1, lc2 = tid & 1;   // Q staging: row, 32-elem half
    int lr = tid >> 2, lc = tid & 3;     // K/V staging: row, 16-elem chunk

    // stage Q (128 x 64 bf16, already scaled by rope)
    {
        const ushort_t* src = qkv + ((size_t)b * L + q0 + lr2) * 3072 + h * 64 + lc2 * 32;
        ushort_t* dst = &Qs[lr2 * 72 + lc2 * 32];
        *(short8*)(dst)      = *(const short8*)(src);
        *(short8*)(dst + 8)  = *(const short8*)(src + 8);
        *(short8*)(dst + 16) = *(const short8*)(src + 16);
        *(short8*)(dst + 24) = *(const short8*)(src + 24);
    }
    __syncthreads();
    short8 aq[2][2];
#pragma unroll
    for (int s = 0; s < 2; ++s)
#pragma unroll
        for (int c = 0; c < 2; ++c)
            aq[s][c] = *(const short8*)&Qs[(wave * 32 + s * 16 + r) * 72 + c * 32 + g * 8];

    // prefetch kt=0 K/V into regs
    const ushort_t* kvbase = qkv + ((size_t)b * L + lr) * 3072 + 1024 + h * 64 + lc * 16;
    short8 kreg0 = *(const short8*)(kvbase);
    short8 kreg1 = *(const short8*)(kvbase + 8);
    short8 vreg0 = *(const short8*)(kvbase + 1024);
    short8 vreg1 = *(const short8*)(kvbase + 1032);

    float m[2][4], lsum[2][4];
    f32x4 acc[2][4];
#pragma unroll
    for (int s = 0; s < 2; ++s)
#pragma unroll
        for (int t = 0; t < 4; ++t) { m[s][t] = -1e30f; lsum[s][t] = 0.f; }
#pragma unroll
    for (int s = 0; s < 2; ++s)
#pragma unroll
        for (int j = 0; j < 4; ++j) acc[s][j] = (f32x4){0.f, 0.f, 0.f, 0.f};

    int ktmax = 2 * qt + 1;
    for (int kt = 0; kt <= ktmax; ++kt) {
        int cb = kt & 1;
        ushort_t* Kc = &Ks[cb][0];
        ushort_t* Vc = &VT[cb][0];
        // write staged regs into current buffers (other waves may still be
        // computing on buffer cb^1 -- safe, disjoint)
        *(short8*)&Kc[lr * 72 + lc * 16]     = kreg0;
        *(short8*)&Kc[lr * 72 + lc * 16 + 8] = kreg1;
#pragma unroll
        for (int i = 0; i < 8; ++i) {
            int row0 = lc * 16 + i;
            int f0 = (row0 & 7) ^ ((row0 >> 4) & 3);
            Vc[row0 * 64 + (((lr >> 3) ^ f0) << 3) + (lr & 7)] = (ushort_t)vreg0[i];
            int row1 = row0 + 8;
            int f1 = (row1 & 7) ^ ((row1 >> 4) & 3);
            Vc[row1 * 64 + (((lr >> 3) ^ f1) << 3) + (lr & 7)] = (ushort_t)vreg1[i];
        }
        asm volatile("s_waitcnt lgkmcnt(0)" ::: "memory");  // ds_writes visible
        __builtin_amdgcn_s_barrier();                        // single barrier/tile
        __builtin_amdgcn_sched_barrier(0);
        // prefetch next tile AFTER the barrier: never drained, hides under compute
        if (kt < ktmax) {
            const ushort_t* p = kvbase + (size_t)(kt + 1) * 64 * 3072;
            kreg0 = *(const short8*)(p);
            kreg1 = *(const short8*)(p + 8);
            vreg0 = *(const short8*)(p + 1024);
            vreg1 = *(const short8*)(p + 1032);
        }

        int k0 = kt * 64;
        // S = Q(2x16x64) . K^T : 8 LDS reads feed 16 MFMAs
        f32x4 s2[2][4];
#pragma unroll
        for (int s = 0; s < 2; ++s)
#pragma unroll
            for (int j = 0; j < 4; ++j) s2[s][j] = (f32x4){0.f, 0.f, 0.f, 0.f};
        __builtin_amdgcn_s_setprio(1);
#pragma unroll
        for (int j = 0; j < 4; ++j)
#pragma unroll
            for (int c = 0; c < 2; ++c) {
                short8 bk = *(const short8*)&Kc[(16 * j + r) * 72 + c * 32 + g * 8];
                s2[0][j] = __builtin_amdgcn_mfma_f32_16x16x32_bf16(aq[0][c], bk, s2[0][j], 0, 0, 0);
                s2[1][j] = __builtin_amdgcn_mfma_f32_16x16x32_bf16(aq[1][c], bk, s2[1][j], 0, 0, 0);
            }
        __builtin_amdgcn_s_setprio(0);

        // causal mask only on the top two tiles
        if (kt >= ktmax - 1) {
#pragma unroll
            for (int s = 0; s < 2; ++s)
#pragma unroll
                for (int j = 0; j < 4; ++j) {
                    int k = k0 + 16 * j + r;
#pragma unroll
                    for (int t = 0; t < 4; ++t)
                        if (k > q0 + wave * 32 + s * 16 + 4 * g + t) s2[s][j][t] = -1e30f;
                }
        }

        // online softmax per strip
        float al[2][4];
#pragma unroll
        for (int s = 0; s < 2; ++s)
#pragma unroll
            for (int t = 0; t < 4; ++t) {
                float rm = fmaxf(fmaxf(s2[s][0][t], s2[s][1][t]), fmaxf(s2[s][2][t], s2[s][3][t]));
#pragma unroll
                for (int o = 8; o > 0; o >>= 1) rm = fmaxf(rm, __shfl_xor(rm, o, 16));
                float mn = fmaxf(m[s][t], rm);
                al[s][t] = __expf(m[s][t] - mn);
                m[s][t] = mn;
                float rs = 0.f;
#pragma unroll
                for (int j = 0; j < 4; ++j) {
                    float p = __expf(s2[s][j][t] - mn);
                    s2[s][j][t] = p;
                    rs += p;
                }
#pragma unroll
                for (int o = 8; o > 0; o >>= 1) rs += __shfl_xor(rs, o, 16);
                lsum[s][t] = lsum[s][t] * al[s][t] + rs;
            }

        // P -> LDS (swizzled), re-read as a-frags (same-wave rows only)
#pragma unroll
        for (int s = 0; s < 2; ++s)
#pragma unroll
            for (int j = 0; j < 4; ++j)
#pragma unroll
                for (int t = 0; t < 4; ++t) {
                    int row = wave * 32 + s * 16 + 4 * g + t;
                    int f = (row >> 1) & 7;
                    Ps[row * 64 + (((2 * j + (r >> 3)) ^ f) << 3) + (r & 7)] = f2bf(s2[s][j][t]);
                }
        short8 ap[2][2];
#pragma unroll
        for (int s = 0; s < 2; ++s) {
            int row = wave * 32 + s * 16 + r;
            int f = (row >> 1) & 7;
#pragma unroll
            for (int c = 0; c < 2; ++c)
                ap[s][c] = *(const short8*)&Ps[row * 64 + (((4 * c + g) ^ f) << 3)];
        }

        // rescale O, then PV: 8 LDS reads feed 16 MFMAs
#pragma unroll
        for (int s = 0; s < 2; ++s)
#pragma unroll
            for (int j = 0; j < 4; ++j)
#pragma unroll
                for (int t = 0; t < 4; ++t) acc[s][j][t] *= al[s][t];
        __builtin_amdgcn_s_setprio(1);
#pragma unroll
        for (int j = 0; j < 4; ++j)
#pragma unroll
            for (int c = 0; c < 2; ++c) {
                int row = 16 * j + r;
                int ch = (4 * c + g) ^ (r & 7) ^ j;
                short8 bv = *(const short8*)&Vc[row * 64 + (ch << 3)];
                acc[0][j] = __builtin_amdgcn_mfma_f32_16x16x32_bf16(ap[0][c], bv, acc[0][j], 0, 0, 0);
                acc[1][j] = __builtin_amdgcn_mfma_f32_16x16x32_bf16(ap[1][c], bv, acc[1][j], 0, 0, 0);
            }
        __builtin_amdgcn_s_setprio(0);
    }

    // epilogue: row = q0+wave*32+s*16+4g+t, col = h*64+16j+r
#pragma unroll
    for (int s = 0; s < 2; ++s)
#pragma unroll
        for (int t = 0; t < 4; ++t) {
            float invl = 1.0f / lsum[s][t];
            size_t orow = ((size_t)b * L + q0 + wave * 32 + s * 16 + 4 * g + t) * 1024 + h * 64;
#pragma unroll
            for (int j = 0; j < 4; ++j)
                out[orow + 16 * j + r] = f2bf(acc[s][j][t] * invl);
        }
}

// ---------------- cross-attention: MFMA, 64q x 64k tiles --------------------
#define AP 72

__global__ __launch_bounds__(256) void cross_attn_mfma(
    const ushort_t* __restrict__ qc, const ushort_t* __restrict__ kvc,
    const int* __restrict__ seg_ids, ushort_t* __restrict__ out, int L, int S) {
    int qt = blockIdx.x, h = blockIdx.y, b = blockIdx.z;
    int q0 = qt * 64;
    __shared__ ushort_t Qs[64 * AP];
    __shared__ ushort_t Ks[64 * AP];
    __shared__ ushort_t VT[64 * AP];
    __shared__ ushort_t Ps[64 * AP];
    __shared__ int segs[64];
    __shared__ int bounds[2];
    int tid = threadIdx.x;
    int wave = tid >> 6, lane = tid & 63;
    int g = lane >> 4, r = lane & 15;
    int lr = tid >> 2, lc = tid & 3;

    {
        const ushort_t* src = qc + ((size_t)b * L + q0 + lr) * 1024 + h * 64 + lc * 16;
        *(short8*)&Qs[lr * AP + lc * 16]     = *(const short8*)(src);
        *(short8*)&Qs[lr * AP + lc * 16 + 8] = *(const short8*)(src + 8);
    }
    if (tid < 64) segs[tid] = seg_ids[(size_t)b * L + q0 + tid];
    __syncthreads();
    if (wave == 0) {
        int v = segs[lane];
        int mn = v, mx = v;
#pragma unroll
        for (int o = 32; o > 0; o >>= 1) {
            mn = min(mn, __shfl_down(mn, o, 64));
            mx = max(mx, __shfl_down(mx, o, 64));
        }
        if (lane == 0) { bounds[0] = mn; bounds[1] = mx; }
    }
    int seg_t[4];
#pragma unroll
    for (int t = 0; t < 4; ++t) seg_t[t] = segs[wave * 16 + 4 * g + t];
    short8 aq[2];
#pragma unroll
    for (int c = 0; c < 2; ++c)
        aq[c] = *(const short8*)&Qs[(wave * 16 + r) * AP + c * 32 + g * 8];
    __syncthreads();
    int lo = bounds[0] - (LOOKBACK - 1); if (lo < 0) lo = 0;
    int t_lo = lo >> 6;
    int t_hi = bounds[1] >> 6;

    float m[4]    = {-1e30f, -1e30f, -1e30f, -1e30f};
    float lsum[4] = {0.f, 0.f, 0.f, 0.f};
    f32x4 acc[4];
#pragma unroll
    for (int j = 0; j < 4; ++j) acc[j] = (f32x4){0.f, 0.f, 0.f, 0.f};

    for (int kt = t_lo; kt <= t_hi; ++kt) {
        int k0 = kt * 64;
        __syncthreads();
        {
            const ushort_t* ksrc = kvc + ((size_t)b * S + k0 + lr) * 2048 + h * 64 + lc * 16;
            short8 k0v = *(const short8*)(ksrc);
            short8 k1v = *(const short8*)(ksrc + 8);
            *(short8*)&Ks[lr * AP + lc * 16]     = k0v;
            *(short8*)&Ks[lr * AP + lc * 16 + 8] = k1v;
            const ushort_t* vsrc = ksrc + 1024;
            short8 v0v = *(const short8*)(vsrc);
            short8 v1v = *(const short8*)(vsrc + 8);
#pragma unroll
            for (int i = 0; i < 8; ++i) {
                VT[(lc * 16 + i) * AP + lr]     = (ushort_t)v0v[i];
                VT[(lc * 16 + 8 + i) * AP + lr] = (ushort_t)v1v[i];
            }
        }
        __syncthreads();

        f32x4 s[4];
#pragma unroll
        for (int j = 0; j < 4; ++j) s[j] = (f32x4){0.f, 0.f, 0.f, 0.f};
#pragma unroll
        for (int j = 0; j < 4; ++j)
#pragma unroll
            for (int c = 0; c < 2; ++c) {
                short8 bk = *(const short8*)&Ks[(16 * j + r) * AP + c * 32 + g * 8];
                s[j] = __builtin_amdgcn_mfma_f32_16x16x32_bf16(aq[c], bk, s[j], 0, 0, 0);
            }

        // scale + window mask: k allowed iff k <= seg && k > seg-LOOKBACK
#pragma unroll
        for (int j = 0; j < 4; ++j) {
            int k = k0 + 16 * j + r;
#pragma unroll
            for (int t = 0; t < 4; ++t) {
                float v = s[j][t] * 0.125f;
                if (k > seg_t[t] || k <= seg_t[t] - LOOKBACK) v = -1e30f;
                s[j][t] = v;
            }
        }

        float al[4];
#pragma unroll
        for (int t = 0; t < 4; ++t) {
            float rm = fmaxf(fmaxf(s[0][t], s[1][t]), fmaxf(s[2][t], s[3][t]));
#pragma unroll
            for (int o = 8; o > 0; o >>= 1) rm = fmaxf(rm, __shfl_xor(rm, o, 16));
            float mn = fmaxf(m[t], rm);
            al[t] = __expf(m[t] - mn);
            m[t] = mn;
            float rs = 0.f;
#pragma unroll
            for (int j = 0; j < 4; ++j) {
                float p = __expf(s[j][t] - mn);
                s[j][t] = p;
                rs += p;
            }
#pragma unroll
            for (int o = 8; o > 0; o >>= 1) rs += __shfl_xor(rs, o, 16);
            lsum[t] = lsum[t] * al[t] + rs;
        }

        ushort_t* pw = &Ps[wave * 16 * AP];
#pragma unroll
        for (int j = 0; j < 4; ++j)
#pragma unroll
            for (int t = 0; t < 4; ++t)
                pw[(4 * g + t) * AP + 16 * j + r] = f2bf(s[j][t]);
        short8 ap[2];
#pragma unroll
        for (int c = 0; c < 2; ++c)
            ap[c] = *(const short8*)&pw[r * AP + c * 32 + g * 8];

#pragma unroll
        for (int j = 0; j < 4; ++j) {
#pragma unroll
            for (int t = 0; t < 4; ++t) acc[j][t] *= al[t];
#pragma unroll
            for (int c = 0; c < 2; ++c) {
                short8 bv = *(const short8*)&VT[(16 * j + r) * AP + c * 32 + g * 8];
                acc[j] = __builtin_amdgcn_mfma_f32_16x16x32_bf16(ap[c], bv, acc[j], 0, 0, 0);
            }
        }
    }

#pragma unroll
    for (int t = 0; t < 4; ++t) {
        float invl = 1.0f / lsum[t];
        size_t orow = ((size_t)b * L + q0 + wave * 16 + 4 * g + t) * 1024 + h * 64;
#pragma unroll
        for (int j = 0; j < 4; ++j)
            out[orow + 16 * j + r] = f2bf(acc[j][t] * invl);
    }
}

// ---------------- driver ----------------
extern "C" void kernel_launch(void* const* d_in, const int* in_sizes, int n_in,
                              void* d_out, int out_size, void* d_ws, size_t ws_size,
                              hipStream_t stream) {
    const int B = 2, L = 2048, S = 256, D = 1024, F = 4096;
    const int BL = B * L;
    const float* x_in   = (const float*)d_in[0];
    const float* memory = (const float*)d_in[1];
    const int*   seg    = (const int*)d_in[2];
    const float* Wqkv = (const float*)d_in[3];
    const float* bqkv = (const float*)d_in[4];
    const float* Wo   = (const float*)d_in[5];
    const float* bo   = (const float*)d_in[6];
    const float* Wq_c = (const float*)d_in[7];
    const float* Wkv_c= (const float*)d_in[8];
    const float* Wo_c = (const float*)d_in[9];
    const float* Wg   = (const float*)d_in[10];
    const float* Wu   = (const float*)d_in[11];
    const float* Wd   = (const float*)d_in[12];
    const float* n1   = (const float*)d_in[13];
    const float* n2   = (const float*)d_in[14];
    const float* n3   = (const float*)d_in[15];
    const float* nf   = (const float*)d_in[16];

    char* ws = (char*)d_ws;
    size_t off = 0;
    float* X     = (float*)(ws + off); off += (size_t)BL * D * 4;        // 16 MB
    float* QKV   = (float*)(ws + off); off += (size_t)BL * 3 * D * 4;    // 48 MB (aliases QKVb, Qcb, Gg)
    float* KVC   = (float*)(ws + off); off += (size_t)B * S * 2 * D * 4; // 4 MB
    ushort_t* Hn  = (ushort_t*)(ws + off); off += (size_t)BL * D * 2;    // 8 MB
    ushort_t* Abf = (ushort_t*)(ws + off); off += (size_t)BL * D * 2;    // 8 MB
    ushort_t* Mb  = (ushort_t*)(ws + off); off += (size_t)B * S * D * 2; // 1 MB
    ushort_t* Wb  = (ushort_t*)(ws + off); off += (size_t)F * D * 2;     // 8 MB
    ushort_t* QKVb = (ushort_t*)QKV;    // bf16 view, self-attn phase
    ushort_t* Qcb  = (ushort_t*)QKV;    // bf16 view, cross phase
    ushort_t* KVCb = (ushort_t*)KVC;    // bf16 view, cross phase
    ushort_t* Gg = (ushort_t*)QKV;      // bf16 view, MLP phase

    hipMemcpyAsync(X, x_in, (size_t)BL * D * sizeof(float), hipMemcpyDeviceToDevice, stream);

    dim3 blk(256);
    // memory -> bf16 once
    f2b_k<<<(B * S * D / 4 + 255) / 256, blk, 0, stream>>>(memory, Mb, B * S * D / 4);

    for (int l = 0; l < N_LAYERS; ++l) {
        // ---- self-attention block ----
        rmsnorm_bf<<<BL, blk, 0, stream>>>(X, n1 + (size_t)l * D, Hn, D);
        f2b_k<<<(3 * D * D / 4 + 255) / 256, blk, 0, stream>>>(
            Wqkv + (size_t)l * 3 * D * D, Wb, 3 * D * D / 4);
        gemm_bf16<<<dim3(3 * D / GBN, BL / GBM), blk, 0, stream>>>(
            Hn, Wb, QKVb, bqkv + (size_t)l * 3 * D, nullptr, nullptr, BL, 3 * D, D, 1);
        int total = BL * NHEADS * 32;
        rope_k<<<(total + 255) / 256, blk, 0, stream>>>(QKVb, L, total);
        self_attn_flash<<<dim3(L / QB, NHEADS, B), blk, 0, stream>>>(QKVb, Abf, L);
        f2b_k<<<(D * D / 4 + 255) / 256, blk, 0, stream>>>(
            Wo + (size_t)l * D * D, Wb, D * D / 4);
        gemm_bf16<<<dim3(D / GBN, BL / GBM), blk, 0, stream>>>(
            Abf, Wb, X, bo + (size_t)l * D, X, nullptr, BL, D, D, 0);
        // ---- cross-attention block ----
        rmsnorm_bf<<<BL, blk, 0, stream>>>(X, n2 + (size_t)l * D, Hn, D);
        f2b_k<<<(D * D / 4 + 255) / 256, blk, 0, stream>>>(
            Wq_c + (size_t)l * D * D, Wb, D * D / 4);
        gemm_bf16<<<dim3(D / GBN, BL / GBM), blk, 0, stream>>>(
            Hn, Wb, Qcb, nullptr, nullptr, nullptr, BL, D, D, 1);
        f2b_k<<<(2 * D * D / 4 + 255) / 256, blk, 0, stream>>>(
            Wkv_c + (size_t)l * 2 * D * D, Wb, 2 * D * D / 4);
        gemm_bf16<<<dim3(2 * D / GBN, B * S / GBM), blk, 0, stream>>>(
            Mb, Wb, KVCb, nullptr, nullptr, nullptr, B * S, 2 * D, D, 1);
        cross_attn_mfma<<<dim3(L / 64, NHEADS, B), blk, 0, stream>>>(
            Qcb, KVCb, seg, Abf, L, S);
        f2b_k<<<(D * D / 4 + 255) / 256, blk, 0, stream>>>(
            Wo_c + (size_t)l * D * D, Wb, D * D / 4);
        gemm_bf16<<<dim3(D / GBN, BL / GBM), blk, 0, stream>>>(
            Abf, Wb, X, nullptr, X, nullptr, BL, D, D, 0);
        // ---- MLP (SwiGLU) ----
        rmsnorm_bf<<<BL, blk, 0, stream>>>(X, n3 + (size_t)l * D, Hn, D);
        f2b_k<<<(F * D / 4 + 255) / 256, blk, 0, stream>>>(
            Wg + (size_t)l * F * D, Wb, F * D / 4);
        gemm_bf16<<<dim3(F / GBN, BL / GBM), blk, 0, stream>>>(
            Hn, Wb, Gg, nullptr, nullptr, nullptr, BL, F, D, 1);
        f2b_k<<<(F * D / 4 + 255) / 256, blk, 0, stream>>>(
            Wu + (size_t)l * F * D, Wb, F * D / 4);
        gemm_bf16<<<dim3(F / GBN, BL / GBM), blk, 0, stream>>>(
            Hn, Wb, Gg, nullptr, nullptr, Gg, BL, F, D, 1);   // silu(g)*u in place
        f2b_k<<<(D * F / 4 + 255) / 256, blk, 0, stream>>>(
            Wd + (size_t)l * D * F, Wb, D * F / 4);
        gemm_bf16<<<dim3(D / GBN, BL / GBM), blk, 0, stream>>>(
            Gg, Wb, X, nullptr, X, nullptr, BL, D, F, 0);
    }
    rmsnorm_k<<<BL, blk, 0, stream>>>(X, nf, (float*)d_out, D);
}

// Round 7
// 2533.151 us; speedup vs baseline: 2.5666x; 1.0732x over previous
//
#include <hip/hip_runtime.h>
#include <hip/hip_bf16.h>
#include <math.h>

#define N_LAYERS 4
#define NHEADS 16
#define LOOKBACK 128

typedef unsigned short ushort_t;
typedef __attribute__((ext_vector_type(8))) short short8;
typedef __attribute__((ext_vector_type(4))) float f32x4;

__device__ __forceinline__ ushort_t f2bf(float f) {
    union { float f; unsigned int u; } v; v.f = f;
    unsigned int r = (v.u + 0x7FFFu + ((v.u >> 16) & 1u)) >> 16;
    return (ushort_t)r;
}
__device__ __forceinline__ float bf2f(ushort_t s) {
    union { unsigned int u; float f; } v; v.u = ((unsigned int)s) << 16;
    return v.f;
}

// ---------------- block reductions (blockDim == 256, 4 waves) ----------------
__device__ __forceinline__ float blk_sum(float v, volatile float* red) {
#pragma unroll
    for (int o = 32; o > 0; o >>= 1) v += __shfl_down(v, o, 64);
    if ((threadIdx.x & 63) == 0) red[threadIdx.x >> 6] = v;
    __syncthreads();
    float r = red[0] + red[1] + red[2] + red[3];
    __syncthreads();
    return r;
}

// ---------------- fp32 -> bf16 convert ----------------
__global__ __launch_bounds__(256) void f2b_k(const float* __restrict__ in,
                                             ushort_t* __restrict__ out, int n4) {
    int i = blockIdx.x * 256 + threadIdx.x;
    if (i >= n4) return;
    float4 v = *(const float4*)(in + (size_t)i * 4);
    ushort_t* o = out + (size_t)i * 4;
    o[0] = f2bf(v.x); o[1] = f2bf(v.y); o[2] = f2bf(v.z); o[3] = f2bf(v.w);
}

// ---------------- RMSNorm -> bf16 out ----------------
__global__ __launch_bounds__(256) void rmsnorm_bf(const float* __restrict__ x,
                                                  const float* __restrict__ w,
                                                  ushort_t* __restrict__ out, int D) {
    __shared__ float red[4];
    size_t row = blockIdx.x;
    const float* xr = x + row * D;
    float ss = 0.f;
    for (int i = threadIdx.x; i < D; i += 256) { float v = xr[i]; ss += v * v; }
    float tot = blk_sum(ss, red);
    float r = rsqrtf(tot / (float)D + 1e-6f);
    ushort_t* o = out + row * D;
    for (int i = threadIdx.x; i < D; i += 256) o[i] = f2bf(xr[i] * r * w[i]);
}

// ---------------- RMSNorm -> fp32 out (final) ----------------
__global__ __launch_bounds__(256) void rmsnorm_k(const float* __restrict__ x,
                                                 const float* __restrict__ w,
                                                 float* __restrict__ out, int D) {
    __shared__ float red[4];
    size_t row = blockIdx.x;
    const float* xr = x + row * D;
    float ss = 0.f;
    for (int i = threadIdx.x; i < D; i += 256) { float v = xr[i]; ss += v * v; }
    float tot = blk_sum(ss, red);
    float r = rsqrtf(tot / (float)D + 1e-6f);
    float* o = out + row * D;
    for (int i = threadIdx.x; i < D; i += 256) o[i] = xr[i] * r * w[i];
}

// ---------------- bf16 MFMA NT-GEMM: dbuf LDS + counted vmcnt (T3/T4) -------
#define GBM 128
#define GBN 128
#define GBK 32

#define STAGE_GEMM(kk, buf) do {                                               \
    const ushort_t* Ag_ = A + (size_t)(bm + srow) * K + (kk) + c4 * 8;         \
    const ushort_t* Bg_ = Bw + (size_t)(bn + srow) * K + (kk) + c4 * 8;        \
    __builtin_amdgcn_global_load_lds(                                          \
        (const __attribute__((address_space(1))) void*)Ag_,                    \
        (__attribute__((address_space(3))) void*)&As[buf][wave * 16 * GBK],    \
        16, 0, 0);                                                             \
    __builtin_amdgcn_global_load_lds(                                          \
        (const __attribute__((address_space(1))) void*)(Ag_ + (size_t)64 * K), \
        (__attribute__((address_space(3))) void*)&As[buf][(64 + wave * 16) * GBK], \
        16, 0, 0);                                                             \
    __builtin_amdgcn_global_load_lds(                                          \
        (const __attribute__((address_space(1))) void*)Bg_,                    \
        (__attribute__((address_space(3))) void*)&Bs[buf][wave * 16 * GBK],    \
        16, 0, 0);                                                             \
    __builtin_amdgcn_global_load_lds(                                          \
        (const __attribute__((address_space(1))) void*)(Bg_ + (size_t)64 * K), \
        (__attribute__((address_space(3))) void*)&Bs[buf][(64 + wave * 16) * GBK], \
        16, 0, 0);                                                             \
} while (0)

__global__ __launch_bounds__(256) void gemm_bf16(
    const ushort_t* __restrict__ A, const ushort_t* __restrict__ Bw,
    void* __restrict__ Cout, const float* __restrict__ bias,
    const float* __restrict__ resid, const ushort_t* __restrict__ gate,
    int M, int N, int K, int out_bf16) {
    __shared__ ushort_t As[2][GBM * GBK];
    __shared__ ushort_t Bs[2][GBN * GBK];
    int tid = threadIdx.x;
    int wave = tid >> 6, lane = tid & 63;
    // bijective XCD swizzle (m204): contiguous grid chunks per XCD
    int nwg = gridDim.x * gridDim.y;
    int wg  = blockIdx.y * gridDim.x + blockIdx.x;
    int qq = nwg >> 3, rr = nwg & 7;
    int xcd = wg & 7, loc = wg >> 3;
    int swz = (xcd < rr ? xcd * (qq + 1) : rr * (qq + 1) + (xcd - rr) * qq) + loc;
    int bm = (swz / gridDim.x) * GBM, bn = (swz % gridDim.x) * GBN;
    int wm = (wave & 1) * 64, wn = (wave >> 1) * 64;
    int r4 = lane >> 2, c4 = lane & 3;        // staging: row-in-16, 16B chunk
    int r = lane & 15, q = lane >> 4;         // mfma lane decomposition

    f32x4 acc[4][4];
#pragma unroll
    for (int i = 0; i < 4; ++i)
#pragma unroll
        for (int j = 0; j < 4; ++j) acc[i][j] = (f32x4){0.f, 0.f, 0.f, 0.f};

    int srow = wave * 16 + r4;
    int nt = K / GBK;
    STAGE_GEMM(0, 0);
    for (int t = 0; t < nt; ++t) {
        int cur = t & 1;
        if (t + 1 < nt) {
            STAGE_GEMM((t + 1) * GBK, cur ^ 1);
            asm volatile("s_waitcnt vmcnt(4)" ::: "memory");   // tile-t loads landed
        } else {
            asm volatile("s_waitcnt vmcnt(0)" ::: "memory");
        }
        __builtin_amdgcn_s_barrier();          // all waves' tile-t loads landed
        __builtin_amdgcn_sched_barrier(0);
        short8 af[4], bfr[4];
#pragma unroll
        for (int i = 0; i < 4; ++i)
            af[i] = *(const short8*)&As[cur][(wm + 16 * i + r) * GBK + q * 8];
#pragma unroll
        for (int j = 0; j < 4; ++j)
            bfr[j] = *(const short8*)&Bs[cur][(wn + 16 * j + r) * GBK + q * 8];
#pragma unroll
        for (int i = 0; i < 4; ++i)
#pragma unroll
            for (int j = 0; j < 4; ++j)
                acc[i][j] = __builtin_amdgcn_mfma_f32_16x16x32_bf16(
                    af[i], bfr[j], acc[i][j], 0, 0, 0);
        __builtin_amdgcn_s_barrier();          // release buf[cur] for overwrite at t+2
        __builtin_amdgcn_sched_barrier(0);
    }
    // epilogue: row = bm+wm+16i+q*4+t, col = bn+wn+16j+r
#pragma unroll
    for (int i = 0; i < 4; ++i) {
#pragma unroll
        for (int j = 0; j < 4; ++j) {
            size_t n = (size_t)(bn + wn + 16 * j + r);
            float bn_v = bias ? bias[n] : 0.f;
#pragma unroll
            for (int t = 0; t < 4; ++t) {
                size_t m = (size_t)(bm + wm + 16 * i + q * 4 + t);
                size_t idx = m * N + n;
                float x = acc[i][j][t] + bn_v;
                if (gate) { float g = bf2f(gate[idx]); x *= g / (1.0f + __expf(-g)); }
                if (resid) x += resid[idx];
                if (out_bf16) ((ushort_t*)Cout)[idx] = f2bf(x);
                else ((float*)Cout)[idx] = x;
            }
        }
    }
}

// ---------------- RoPE in place on bf16 qkv; Q also scaled by 1/sqrt(d) -----
__global__ void rope_k(ushort_t* __restrict__ qkv, int L, int total) {
    int idx = blockIdx.x * 256 + threadIdx.x;
    if (idx >= total) return;
    int d = idx & 31;
    int h = (idx >> 5) & 15;
    int bl = idx >> 9;
    int l = bl % L;
    float inv = exp2f(-(float)d * (13.2877123795f / 32.0f));
    float f = (float)l * inv;
    float s, c;
    sincosf(f, &s, &c);
    ushort_t* base = qkv + (size_t)bl * 3072 + h * 64 + d;
    float x1 = bf2f(base[0]), x2 = bf2f(base[32]);
    base[0]  = f2bf((x1 * c - x2 * s) * 0.125f);   // Q pre-scaled
    base[32] = f2bf((x2 * c + x1 * s) * 0.125f);
    ushort_t* kb = base + 1024;
    x1 = bf2f(kb[0]); x2 = bf2f(kb[32]);
    kb[0]  = f2bf(x1 * c - x2 * s);
    kb[32] = f2bf(x2 * c + x1 * s);
}

// ---------------- flash self-attention: MFMA, 64q x 64k, paired q-tiles -----
// Each block handles q-tiles `pair` and `31-pair` (uniform 33 k-tile-units),
// eliminating the tail where one CU holds two qt=15 blocks. Q a-frags load
// straight from global (no Qs LDS). K/V dbuf LDS, one raw barrier per tile,
// reg prefetch after the barrier. lsum kept as per-lane partial, reduced in
// the epilogue. Defer-max (T13, THR=8) skips the rescale pass when possible.
__global__ __launch_bounds__(256) void self_attn_flash(
    const ushort_t* __restrict__ qkv, ushort_t* __restrict__ out, int L) {
    int lin = blockIdx.x + gridDim.x * (blockIdx.y + gridDim.y * blockIdx.z);
    int xcd = lin & 7, slot = lin >> 3;
    int pair = slot & 15;             // q-tile pair id (16 pairs of 64-row tiles)
    int grp = xcd + 8 * (slot >> 4);  // 0..31 -> same (b,h) pinned to one XCD
    int h = grp & 15, b = grp >> 4;

    __shared__ ushort_t Ks[2][64 * 72];
    __shared__ ushort_t VT[2][64 * 64];   // swizzled, VT[d][k]=V[k][d]
    __shared__ ushort_t Ps[64 * 64];      // swizzled, per-wave rows

    int tid = threadIdx.x;
    int wave = tid >> 6, lane = tid & 63;
    int g = lane >> 4, r = lane & 15;
    int lr = tid >> 2, lc = tid & 3;      // K/V staging: row, 16-elem chunk

    const ushort_t* kvbase = qkv + ((size_t)b * L + lr) * 3072 + 1024 + h * 64 + lc * 16;

    for (int ph = 0; ph < 2; ++ph) {
        int qt = ph ? 31 - pair : pair;
        int q0 = qt * 64;

        // Q a-frags direct from global (already rope'd + 1/sqrt(d)-scaled)
        const ushort_t* qrow = qkv + ((size_t)b * L + q0 + wave * 16 + r) * 3072 + h * 64 + g * 8;
        short8 aq0 = *(const short8*)(qrow);
        short8 aq1 = *(const short8*)(qrow + 32);

        // prefetch kt=0 K/V into regs (no LDS hazard -> before the phase barrier)
        short8 kreg0 = *(const short8*)(kvbase);
        short8 kreg1 = *(const short8*)(kvbase + 8);
        short8 vreg0 = *(const short8*)(kvbase + 1024);
        short8 vreg1 = *(const short8*)(kvbase + 1032);

        if (ph) {  // protect LDS buffers against phase-0 stragglers
            __builtin_amdgcn_s_barrier();
            __builtin_amdgcn_sched_barrier(0);
        }

        float m[4]  = {-1e30f, -1e30f, -1e30f, -1e30f};
        float lp[4] = {0.f, 0.f, 0.f, 0.f};   // per-lane partial denominator
        f32x4 acc[4];
#pragma unroll
        for (int j = 0; j < 4; ++j) acc[j] = (f32x4){0.f, 0.f, 0.f, 0.f};

        for (int kt = 0; kt <= qt; ++kt) {
            int cb = kt & 1;
            ushort_t* Kc = &Ks[cb][0];
            ushort_t* Vc = &VT[cb][0];
            *(short8*)&Kc[lr * 72 + lc * 16]     = kreg0;
            *(short8*)&Kc[lr * 72 + lc * 16 + 8] = kreg1;
#pragma unroll
            for (int i = 0; i < 8; ++i) {
                int row0 = lc * 16 + i;
                int f0 = (row0 & 7) ^ ((row0 >> 4) & 3);
                Vc[row0 * 64 + (((lr >> 3) ^ f0) << 3) + (lr & 7)] = (ushort_t)vreg0[i];
                int row1 = row0 + 8;
                int f1 = (row1 & 7) ^ ((row1 >> 4) & 3);
                Vc[row1 * 64 + (((lr >> 3) ^ f1) << 3) + (lr & 7)] = (ushort_t)vreg1[i];
            }
            asm volatile("s_waitcnt lgkmcnt(0)" ::: "memory");
            __builtin_amdgcn_s_barrier();     // single barrier per tile
            __builtin_amdgcn_sched_barrier(0);
            if (kt < qt) {                    // prefetch rides under compute
                const ushort_t* p = kvbase + (size_t)(kt + 1) * 64 * 3072;
                kreg0 = *(const short8*)(p);
                kreg1 = *(const short8*)(p + 8);
                vreg0 = *(const short8*)(p + 1024);
                vreg1 = *(const short8*)(p + 1032);
            }

            // S = Q(16x64) . K^T(64x64): 8 LDS reads, 8 MFMAs
            f32x4 s[4];
#pragma unroll
            for (int j = 0; j < 4; ++j) s[j] = (f32x4){0.f, 0.f, 0.f, 0.f};
            __builtin_amdgcn_s_setprio(1);
#pragma unroll
            for (int j = 0; j < 4; ++j) {
                short8 bk0 = *(const short8*)&Kc[(16 * j + r) * 72 + g * 8];
                s[j] = __builtin_amdgcn_mfma_f32_16x16x32_bf16(aq0, bk0, s[j], 0, 0, 0);
                short8 bk1 = *(const short8*)&Kc[(16 * j + r) * 72 + 32 + g * 8];
                s[j] = __builtin_amdgcn_mfma_f32_16x16x32_bf16(aq1, bk1, s[j], 0, 0, 0);
            }
            __builtin_amdgcn_s_setprio(0);

            if (kt == qt) {   // causal mask on the diagonal tile
#pragma unroll
                for (int j = 0; j < 4; ++j)
#pragma unroll
                    for (int t = 0; t < 4; ++t)
                        if (16 * j + r > wave * 16 + 4 * g + t) s[j][t] = -1e30f;
            }

            // online softmax: max-reduce (required), rescale only when needed
            float rm[4];
            bool need = false;
#pragma unroll
            for (int t = 0; t < 4; ++t) {
                float x = fmaxf(fmaxf(s[0][t], s[1][t]), fmaxf(s[2][t], s[3][t]));
#pragma unroll
                for (int o = 8; o > 0; o >>= 1) x = fmaxf(x, __shfl_xor(x, o, 16));
                rm[t] = x;
                need = need || (x > m[t] + 8.f);
            }
            if (__any((int)need)) {
#pragma unroll
                for (int t = 0; t < 4; ++t) {
                    float mn = fmaxf(m[t], rm[t]);
                    float al = __expf(m[t] - mn);
                    m[t] = mn;
                    lp[t] *= al;
#pragma unroll
                    for (int j = 0; j < 4; ++j) acc[j][t] *= al;
                }
            }
#pragma unroll
            for (int t = 0; t < 4; ++t) {
#pragma unroll
                for (int j = 0; j < 4; ++j) {
                    float p = __expf(s[j][t] - m[t]);
                    s[j][t] = p;
                    lp[t] += p;
                }
            }

            // P -> LDS (swizzled), re-read as a-frags (same-wave rows only)
#pragma unroll
            for (int j = 0; j < 4; ++j)
#pragma unroll
                for (int t = 0; t < 4; ++t) {
                    int row = wave * 16 + 4 * g + t;
                    int f = (row >> 1) & 7;
                    Ps[row * 64 + (((2 * j + (r >> 3)) ^ f) << 3) + (r & 7)] = f2bf(s[j][t]);
                }
            short8 ap0, ap1;
            {
                int row = wave * 16 + r;
                int f = (row >> 1) & 7;
                ap0 = *(const short8*)&Ps[row * 64 + ((g ^ f) << 3)];
                ap1 = *(const short8*)&Ps[row * 64 + (((4 + g) ^ f) << 3)];
            }

            // PV: 8 LDS reads, 8 MFMAs
            __builtin_amdgcn_s_setprio(1);
#pragma unroll
            for (int j = 0; j < 4; ++j) {
                int rowv = 16 * j + r;
                int ch0 = g ^ (r & 7) ^ j;
                short8 bv0 = *(const short8*)&Vc[rowv * 64 + (ch0 << 3)];
                acc[j] = __builtin_amdgcn_mfma_f32_16x16x32_bf16(ap0, bv0, acc[j], 0, 0, 0);
                int ch1 = (4 + g) ^ (r & 7) ^ j;
                short8 bv1 = *(const short8*)&Vc[rowv * 64 + (ch1 << 3)];
                acc[j] = __builtin_amdgcn_mfma_f32_16x16x32_bf16(ap1, bv1, acc[j], 0, 0, 0);
            }
            __builtin_amdgcn_s_setprio(0);
        }

        // epilogue: reduce deferred denominator, write out
#pragma unroll
        for (int t = 0; t < 4; ++t) {
            float tot = lp[t];
#pragma unroll
            for (int o = 8; o > 0; o >>= 1) tot += __shfl_xor(tot, o, 16);
            float invl = 1.0f / tot;
            size_t orow = ((size_t)b * L + q0 + wave * 16 + 4 * g + t) * 1024 + h * 64;
#pragma unroll
            for (int j = 0; j < 4; ++j)
                out[orow + 16 * j + r] = f2bf(acc[j][t] * invl);
        }
    }
}

// ---------------- cross-attention: MFMA, 64q x 64k tiles --------------------
#define AP 72

__global__ __launch_bounds__(256) void cross_attn_mfma(
    const ushort_t* __restrict__ qc, const ushort_t* __restrict__ kvc,
    const int* __restrict__ seg_ids, ushort_t* __restrict__ out, int L, int S) {
    int qt = blockIdx.x, h = blockIdx.y, b = blockIdx.z;
    int q0 = qt * 64;
    __shared__ ushort_t Qs[64 * AP];
    __shared__ ushort_t Ks[64 * AP];
    __shared__ ushort_t VT[64 * AP];
    __shared__ ushort_t Ps[64 * AP];
    __shared__ int segs[64];
    __shared__ int bounds[2];
    int tid = threadIdx.x;
    int wave = tid >> 6, lane = tid & 63;
    int g = lane >> 4, r = lane & 15;
    int lr = tid >> 2, lc = tid & 3;

    {
        const ushort_t* src = qc + ((size_t)b * L + q0 + lr) * 1024 + h * 64 + lc * 16;
        *(short8*)&Qs[lr * AP + lc * 16]     = *(const short8*)(src);
        *(short8*)&Qs[lr * AP + lc * 16 + 8] = *(const short8*)(src + 8);
    }
    if (tid < 64) segs[tid] = seg_ids[(size_t)b * L + q0 + tid];
    __syncthreads();
    if (wave == 0) {
        int v = segs[lane];
        int mn = v, mx = v;
#pragma unroll
        for (int o = 32; o > 0; o >>= 1) {
            mn = min(mn, __shfl_down(mn, o, 64));
            mx = max(mx, __shfl_down(mx, o, 64));
        }
        if (lane == 0) { bounds[0] = mn; bounds[1] = mx; }
    }
    int seg_t[4];
#pragma unroll
    for (int t = 0; t < 4; ++t) seg_t[t] = segs[wave * 16 + 4 * g + t];
    short8 aq[2];
#pragma unroll
    for (int c = 0; c < 2; ++c)
        aq[c] = *(const short8*)&Qs[(wave * 16 + r) * AP + c * 32 + g * 8];
    __syncthreads();
    int lo = bounds[0] - (LOOKBACK - 1); if (lo < 0) lo = 0;
    int t_lo = lo >> 6;
    int t_hi = bounds[1] >> 6;

    float m[4]    = {-1e30f, -1e30f, -1e30f, -1e30f};
    float lsum[4] = {0.f, 0.f, 0.f, 0.f};
    f32x4 acc[4];
#pragma unroll
    for (int j = 0; j < 4; ++j) acc[j] = (f32x4){0.f, 0.f, 0.f, 0.f};

    for (int kt = t_lo; kt <= t_hi; ++kt) {
        int k0 = kt * 64;
        __syncthreads();
        {
            const ushort_t* ksrc = kvc + ((size_t)b * S + k0 + lr) * 2048 + h * 64 + lc * 16;
            short8 k0v = *(const short8*)(ksrc);
            short8 k1v = *(const short8*)(ksrc + 8);
            *(short8*)&Ks[lr * AP + lc * 16]     = k0v;
            *(short8*)&Ks[lr * AP + lc * 16 + 8] = k1v;
            const ushort_t* vsrc = ksrc + 1024;
            short8 v0v = *(const short8*)(vsrc);
            short8 v1v = *(const short8*)(vsrc + 8);
#pragma unroll
            for (int i = 0; i < 8; ++i) {
                VT[(lc * 16 + i) * AP + lr]     = (ushort_t)v0v[i];
                VT[(lc * 16 + 8 + i) * AP + lr] = (ushort_t)v1v[i];
            }
        }
        __syncthreads();

        f32x4 s[4];
#pragma unroll
        for (int j = 0; j < 4; ++j) s[j] = (f32x4){0.f, 0.f, 0.f, 0.f};
#pragma unroll
        for (int j = 0; j < 4; ++j)
#pragma unroll
            for (int c = 0; c < 2; ++c) {
                short8 bk = *(const short8*)&Ks[(16 * j + r) * AP + c * 32 + g * 8];
                s[j] = __builtin_amdgcn_mfma_f32_16x16x32_bf16(aq[c], bk, s[j], 0, 0, 0);
            }

        // scale + window mask: k allowed iff k <= seg && k > seg-LOOKBACK
#pragma unroll
        for (int j = 0; j < 4; ++j) {
            int k = k0 + 16 * j + r;
#pragma unroll
            for (int t = 0; t < 4; ++t) {
                float v = s[j][t] * 0.125f;
                if (k > seg_t[t] || k <= seg_t[t] - LOOKBACK) v = -1e30f;
                s[j][t] = v;
            }
        }

        float al[4];
#pragma unroll
        for (int t = 0; t < 4; ++t) {
            float rm = fmaxf(fmaxf(s[0][t], s[1][t]), fmaxf(s[2][t], s[3][t]));
#pragma unroll
            for (int o = 8; o > 0; o >>= 1) rm = fmaxf(rm, __shfl_xor(rm, o, 16));
            float mn = fmaxf(m[t], rm);
            al[t] = __expf(m[t] - mn);
            m[t] = mn;
            float rs = 0.f;
#pragma unroll
            for (int j = 0; j < 4; ++j) {
                float p = __expf(s[j][t] - mn);
                s[j][t] = p;
                rs += p;
            }
#pragma unroll
            for (int o = 8; o > 0; o >>= 1) rs += __shfl_xor(rs, o, 16);
            lsum[t] = lsum[t] * al[t] + rs;
        }

        ushort_t* pw = &Ps[wave * 16 * AP];
#pragma unroll
        for (int j = 0; j < 4; ++j)
#pragma unroll
            for (int t = 0; t < 4; ++t)
                pw[(4 * g + t) * AP + 16 * j + r] = f2bf(s[j][t]);
        short8 ap[2];
#pragma unroll
        for (int c = 0; c < 2; ++c)
            ap[c] = *(const short8*)&pw[r * AP + c * 32 + g * 8];

#pragma unroll
        for (int j = 0; j < 4; ++j) {
#pragma unroll
            for (int t = 0; t < 4; ++t) acc[j][t] *= al[t];
#pragma unroll
            for (int c = 0; c < 2; ++c) {
                short8 bv = *(const short8*)&VT[(16 * j + r) * AP + c * 32 + g * 8];
                acc[j] = __builtin_amdgcn_mfma_f32_16x16x32_bf16(ap[c], bv, acc[j], 0, 0, 0);
            }
        }
    }

#pragma unroll
    for (int t = 0; t < 4; ++t) {
        float invl = 1.0f / lsum[t];
        size_t orow = ((size_t)b * L + q0 + wave * 16 + 4 * g + t) * 1024 + h * 64;
#pragma unroll
        for (int j = 0; j < 4; ++j)
            out[orow + 16 * j + r] = f2bf(acc[j][t] * invl);
    }
}

// ---------------- driver ----------------
extern "C" void kernel_launch(void* const* d_in, const int* in_sizes, int n_in,
                              void* d_out, int out_size, void* d_ws, size_t ws_size,
                              hipStream_t stream) {
    const int B = 2, L = 2048, S = 256, D = 1024, F = 4096;
    const int BL = B * L;
    const float* x_in   = (const float*)d_in[0];
    const float* memory = (const float*)d_in[1];
    const int*   seg    = (const int*)d_in[2];
    const float* Wqkv = (const float*)d_in[3];
    const float* bqkv = (const float*)d_in[4];
    const float* Wo   = (const float*)d_in[5];
    const float* bo   = (const float*)d_in[6];
    const float* Wq_c = (const float*)d_in[7];
    const float* Wkv_c= (const float*)d_in[8];
    const float* Wo_c = (const float*)d_in[9];
    const float* Wg   = (const float*)d_in[10];
    const float* Wu   = (const float*)d_in[11];
    const float* Wd   = (const float*)d_in[12];
    const float* n1   = (const float*)d_in[13];
    const float* n2   = (const float*)d_in[14];
    const float* n3   = (const float*)d_in[15];
    const float* nf   = (const float*)d_in[16];

    char* ws = (char*)d_ws;
    size_t off = 0;
    float* X     = (float*)(ws + off); off += (size_t)BL * D * 4;        // 16 MB
    float* QKV   = (float*)(ws + off); off += (size_t)BL * 3 * D * 4;    // 48 MB (aliases QKVb, Qcb, Gg)
    float* KVC   = (float*)(ws + off); off += (size_t)B * S * 2 * D * 4; // 4 MB
    ushort_t* Hn  = (ushort_t*)(ws + off); off += (size_t)BL * D * 2;    // 8 MB
    ushort_t* Abf = (ushort_t*)(ws + off); off += (size_t)BL * D * 2;    // 8 MB
    ushort_t* Mb  = (ushort_t*)(ws + off); off += (size_t)B * S * D * 2; // 1 MB
    ushort_t* Wb  = (ushort_t*)(ws + off); off += (size_t)F * D * 2;     // 8 MB
    ushort_t* QKVb = (ushort_t*)QKV;    // bf16 view, self-attn phase
    ushort_t* Qcb  = (ushort_t*)QKV;    // bf16 view, cross phase
    ushort_t* KVCb = (ushort_t*)KVC;    // bf16 view, cross phase
    ushort_t* Gg = (ushort_t*)QKV;      // bf16 view, MLP phase

    hipMemcpyAsync(X, x_in, (size_t)BL * D * sizeof(float), hipMemcpyDeviceToDevice, stream);

    dim3 blk(256);
    // memory -> bf16 once
    f2b_k<<<(B * S * D / 4 + 255) / 256, blk, 0, stream>>>(memory, Mb, B * S * D / 4);

    for (int l = 0; l < N_LAYERS; ++l) {
        // ---- self-attention block ----
        rmsnorm_bf<<<BL, blk, 0, stream>>>(X, n1 + (size_t)l * D, Hn, D);
        f2b_k<<<(3 * D * D / 4 + 255) / 256, blk, 0, stream>>>(
            Wqkv + (size_t)l * 3 * D * D, Wb, 3 * D * D / 4);
        gemm_bf16<<<dim3(3 * D / GBN, BL / GBM), blk, 0, stream>>>(
            Hn, Wb, QKVb, bqkv + (size_t)l * 3 * D, nullptr, nullptr, BL, 3 * D, D, 1);
        int total = BL * NHEADS * 32;
        rope_k<<<(total + 255) / 256, blk, 0, stream>>>(QKVb, L, total);
        self_attn_flash<<<dim3(L / 128, NHEADS, B), blk, 0, stream>>>(QKVb, Abf, L);
        f2b_k<<<(D * D / 4 + 255) / 256, blk, 0, stream>>>(
            Wo + (size_t)l * D * D, Wb, D * D / 4);
        gemm_bf16<<<dim3(D / GBN, BL / GBM), blk, 0, stream>>>(
            Abf, Wb, X, bo + (size_t)l * D, X, nullptr, BL, D, D, 0);
        // ---- cross-attention block ----
        rmsnorm_bf<<<BL, blk, 0, stream>>>(X, n2 + (size_t)l * D, Hn, D);
        f2b_k<<<(D * D / 4 + 255) / 256, blk, 0, stream>>>(
            Wq_c + (size_t)l * D * D, Wb, D * D / 4);
        gemm_bf16<<<dim3(D / GBN, BL / GBM), blk, 0, stream>>>(
            Hn, Wb, Qcb, nullptr, nullptr, nullptr, BL, D, D, 1);
        f2b_k<<<(2 * D * D / 4 + 255) / 256, blk, 0, stream>>>(
            Wkv_c + (size_t)l * 2 * D * D, Wb, 2 * D * D / 4);
        gemm_bf16<<<dim3(2 * D / GBN, B * S / GBM), blk, 0, stream>>>(
            Mb, Wb, KVCb, nullptr, nullptr, nullptr, B * S, 2 * D, D, 1);
        cross_attn_mfma<<<dim3(L / 64, NHEADS, B), blk, 0, stream>>>(
            Qcb, KVCb, seg, Abf, L, S);
        f2b_k<<<(D * D / 4 + 255) / 256, blk, 0, stream>>>(
            Wo_c + (size_t)l * D * D, Wb, D * D / 4);
        gemm_bf16<<<dim3(D / GBN, BL / GBM), blk, 0, stream>>>(
            Abf, Wb, X, nullptr, X, nullptr, BL, D, D, 0);
        // ---- MLP (SwiGLU) ----
        rmsnorm_bf<<<BL, blk, 0, stream>>>(X, n3 + (size_t)l * D, Hn, D);
        f2b_k<<<(F * D / 4 + 255) / 256, blk, 0, stream>>>(
            Wg + (size_t)l * F * D, Wb, F * D / 4);
        gemm_bf16<<<dim3(F / GBN, BL / GBM), blk, 0, stream>>>(
            Hn, Wb, Gg, nullptr, nullptr, nullptr, BL, F, D, 1);
        f2b_k<<<(F * D / 4 + 255) / 256, blk, 0, stream>>>(
            Wu + (size_t)l * F * D, Wb, F * D / 4);
        gemm_bf16<<<dim3(F / GBN, BL / GBM), blk, 0, stream>>>(
            Hn, Wb, Gg, nullptr, nullptr, Gg, BL, F, D, 1);   // silu(g)*u in place
        f2b_k<<<(D * F / 4 + 255) / 256, blk, 0, stream>>>(
            Wd + (size_t)l * D * F, Wb, D * F / 4);
        gemm_bf16<<<dim3(D / GBN, BL / GBM), blk, 0, stream>>>(
            Gg, Wb, X, nullptr, X, nullptr, BL, D, F, 0);
    }
    rmsnorm_k<<<BL, blk, 0, stream>>>(X, nf, (float*)d_out, D);
}